// Round 8
// baseline (554.196 us; speedup 1.0000x reference)
//
#include <hip/hip_runtime.h>
#include <math.h>

#define NN 1000
#define INF_ 32
#define H 128
#define M 128
#define DEG 16
#define PP 2
#define OUTF 10
#define MAXM (10 * NN)        // scan length; head <= MAXM
#define QCAP (MAXM + DEG)     // only entries < MAXM are ever read
#define NSLOT (MAXM + 128)    // nmbuf rows: nstart + total procs
#define NT 512
#define WQ (2 * NT)           // window size: 2 queue entries per thread
#define WROW 264              // padded halves per X/weight row (256+8)
#define NROW 136              // padded halves per NSh row (128+8)

typedef _Float16 half8 __attribute__((ext_vector_type(8)));
typedef float floatx4 __attribute__((ext_vector_type(4)));

// LDS-only barrier: publishes LDS writes without draining global (vmcnt) queue.
__device__ __forceinline__ void bar_lds() {
    asm volatile("s_waitcnt lgkmcnt(0)\n\ts_barrier" ::: "memory");
}

__global__ __launch_bounds__(128)
void init_kernel(const float* __restrict__ xa, const float* __restrict__ fm,
                 const float* __restrict__ enc_w, const float* __restrict__ enc_b,
                 const int* __restrict__ nstart_p,
                 _Float16* __restrict__ feats_h, float* __restrict__ finalv,
                 _Float16* __restrict__ nmbuf_h) {
    int b = blockIdx.x, t = threadIdx.x;
    float acc = enc_b[t];
    const float* xr = xa + b * INF_;
#pragma unroll
    for (int k = 0; k < INF_; ++k) acc += xr[k] * enc_w[k * H + t];
    feats_h[b * H + t] = (_Float16)acc;     // same rounding point as before
    finalv[b * H + t] = 0.0f;
    if (b < nstart_p[0]) nmbuf_h[(size_t)b * M + t] = (_Float16)fm[b * M + t];
}

// Pack weights fp16 transposed [n][k] with +8 pad: wB[n*WROW+k] = w[k][n].
__global__ __launch_bounds__(256)
void pack_kernel(const float* __restrict__ ns_w, const float* __restrict__ nm_w,
                 _Float16* __restrict__ wnsB, _Float16* __restrict__ wnmB) {
    const int idx = blockIdx.x * 256 + threadIdx.x;   // 128*WROW
    if (idx >= 128 * WROW) return;
    const int n = idx / WROW, k = idx % WROW;
    wnsB[idx] = (k < 256) ? (_Float16)ns_w[k * H + n] : (_Float16)0.0f;
    wnmB[idx] = (k < 256) ? (_Float16)nm_w[k * M + n] : (_Float16)0.0f;
}

// Rank-decomposed sequential ACT loop; MFMA matvecs with REGISTER-RESIDENT
// weight B-fragments; LDS-only fine barriers; LDS message queue.
// R7 (on R6's lean pipeline):
//  - 32-row SUPERCHUNK per barrier segment (two independent 16-row tiles
//    L/U): 4 independent MFMA chains per wave per segment; segment count
//    halves. Per-row VALU unchanged (full-tile specialization + 1-thread/row
//    gate retained).
//  - vmcnt drain relocated: R7 is now LDS-only; s_waitcnt vmcnt(0) sits just
//    before R1's barrier, overlapped by rank-round classify/atomicMin work.
__global__ __launch_bounds__(NT, 1)
void seq_kernel(const int* __restrict__ neighbors,
                const float* __restrict__ ns_b, const float* __restrict__ nm_b,
                const float* __restrict__ act_w, const float* __restrict__ act_b,
                const float* __restrict__ dec_w, const float* __restrict__ dec_b,
                const int* __restrict__ nstart_p,
                const _Float16* __restrict__ wnsB, const _Float16* __restrict__ wnmB,
                _Float16* __restrict__ feats_h, float* __restrict__ finalv,
                _Float16* __restrict__ nmbuf_h, unsigned int* __restrict__ qpack_unused,
                float* __restrict__ out) {
    __shared__ __align__(16) _Float16 s_Xh[2][32 * WROW];   // 33792 B
    __shared__ __align__(16) _Float16 s_NSh[2][32 * NROW];  // 17408 B
    __shared__ unsigned int s_q[QCAP];                      // 40064 B (LDS queue)
    __shared__ float s_tact[NN];                            // 4000 B
    __shared__ int   s_mark[NN];                            // 4000 B (order/readout overlay)
    __shared__ float s_actw[H + M];
    __shared__ float s_nsb[H];
    __shared__ float s_nmb[M];
    __shared__ float s_rna[2][32];
    __shared__ unsigned short s_rns[2 * WQ];                // [0]=node, [WQ]=slot, rank order
    __shared__ unsigned int  s_enq[WQ];                     // node|newslot<<16 per entry
    __shared__ unsigned char s_flag[NT];                    // bit0: entry t, bit1: entry 512+t
    __shared__ int s_wc[8], s_wd[8];
    __shared__ int s_cnt;

    unsigned short* const s_rnode = s_rns;
    short* s_order = (short*)s_mark;                     // overlay: mark[0..511] = 1024 shorts
    float* s_g  = (float*)(s_mark + 512);                // overlay: readout only
    float* s_lg = (float*)(s_mark + 512 + 128);

    const int t = threadIdx.x;
    const int lane = t & 63, wid = t >> 6;
    const int quad = lane >> 4, lm = lane & 15;
    const int q4 = quad << 2;
    const int colw = (wid << 4) + lm;                    // this thread's output col
    const int sg = t & 31;                               // gate sub-lane
    const int r16 = t >> 5, c8 = t & 31;                 // staging coords (16x32)
    const int nstart = nstart_p[0];
    // loop-invariant staging source (feats row stride == nmbuf row stride == 128 halves)
    const int rsoff = (c8 < 16) ? 0 : WQ;
    const _Float16* const gsrc = (c8 < 16) ? (feats_h + c8 * 8)
                                           : (nmbuf_h + (c8 - 16) * 8);

    // ---- one-time: weight B-fragments into registers (loop-invariant) ----
    half8 wbn[8], wbm[8];
#pragma unroll
    for (int c = 0; c < 8; ++c) {
        wbn[c] = *(const half8*)(wnsB + (size_t)colw * WROW + (c << 5) + (quad << 3));
        wbm[c] = *(const half8*)(wnmB + (size_t)colw * WROW + (c << 5) + (quad << 3));
    }

    for (int i = t; i < NN; i += NT) { s_tact[i] = 0.0f; s_mark[i] = 0x7fffffff; }
    for (int i = t; i < nstart; i += NT) s_q[i] = (unsigned)i | ((unsigned)i << 16);
    if (t < H + M) s_actw[t] = act_w[t];
    if (t < H) { s_nsb[t] = ns_b[t]; s_nmb[t] = nm_b[t]; }
    const float actb = act_b[0];
    __syncthreads();
    const float nsb_c = s_nsb[colw];
    const float nmb_c = s_nmb[colw];
    float aw[8];
#pragma unroll
    for (int j = 0; j < 8; ++j) aw[j] = s_actw[sg * 8 + j];

    // gate partial from staging registers (bitwise == old LDS-read path)
    auto gate = [&](uint4 v) -> float {
        const half8 hv = *(const half8*)&v;
        float p = 0.0f;
#pragma unroll
        for (int j = 0; j < 8; ++j) p += (float)hv[j] * aw[j];
#pragma unroll
        for (int off = 16; off > 0; off >>= 1) p += __shfl_down(p, off, 32);
        return p;                                        // valid in sg==0
    };

    int head = 0, tail = nstart, gbase = nstart;
    for (;;) {
        const int lim = min(tail, MAXM);
        if (head >= lim) break;
        const int W = min(WQ, lim - head);

        // ---- classify both entries; clear flags; repair order-overlaid mark ----
        int nodeA = 0, slotA = 0; bool remA = false;
        int nodeB = 0, slotB = 0; bool remB = false;
        if (t < W) {
            const unsigned v = s_q[head + t];
            nodeA = (int)(v & 0xffffu);
            slotA = (int)(v >> 16);
            remA = (s_tact[nodeA] <= 1.0f - 1e-7f);
        }
        if (NT + t < W) {
            const unsigned v = s_q[head + NT + t];
            nodeB = (int)(v & 0xffffu);
            slotB = (int)(v >> 16);
            remB = (s_tact[nodeB] <= 1.0f - 1e-7f);
        }
        s_flag[t] = 0;
        s_mark[t] = 0x7fffffff;                          // repair overlay (t<512 region)
        bar_lds();                                       // B1

        // ---------------- rank rounds ----------------
        int base = 0;
        for (;;) {
            const bool rem2a = remA && (s_tact[nodeA] <= 1.0f - 1e-7f);
            const bool rem2b = remB && (s_tact[nodeB] <= 1.0f - 1e-7f);
            if (rem2a) atomicMin(&s_mark[nodeA], t);
            if (rem2b) atomicMin(&s_mark[nodeB], NT + t);
            if (t == 0) s_cnt = 0;
            // drain prior rounds' global stores here (overlapped by the work
            // above); the following barrier then publishes them block-wide.
            asm volatile("s_waitcnt vmcnt(0)" ::: "memory");
            bar_lds();                                   // R1
            const bool winA = rem2a && (s_mark[nodeA] == t);
            const bool winB = rem2b && (s_mark[nodeB] == NT + t);
            const unsigned long long ma = __ballot(winA);
            const unsigned long long mb = __ballot(winB);
            const int ca = __popcll(ma), cb = __popcll(mb);
            int wbase = 0;
            if (lane == 0 && (ca + cb)) wbase = atomicAdd(&s_cnt, ca + cb);
            wbase = __shfl(wbase, 0, 64);
            const unsigned long long below = (1ull << lane) - 1ull;
            if (winA) {
                const int wrank = wbase + __popcll(ma & below);
                s_rns[wrank] = (unsigned short)nodeA;
                s_rns[WQ + wrank] = (unsigned short)slotA;
                s_enq[t] = (unsigned)nodeA | ((unsigned)(gbase + base + wrank) << 16);
                s_flag[t] |= 1;
            }
            if (winB) {
                const int wrank = wbase + ca + __popcll(mb & below);
                s_rns[wrank] = (unsigned short)nodeB;
                s_rns[WQ + wrank] = (unsigned short)slotB;
                s_enq[NT + t] = (unsigned)nodeB | ((unsigned)(gbase + base + wrank) << 16);
                s_flag[t] |= 2;
            }
            remA = rem2a && !winA;
            remB = rem2b && !winB;
            bar_lds();                                   // R3: rnode/rslot/cnt ready
            if (rem2a) s_mark[nodeA] = 0x7fffffff;       // reset (barrier-separated)
            if (rem2b) s_mark[nodeB] = 0x7fffffff;
            const int Pr = s_cnt;
            if (Pr == 0) break;

            // ============ single-barrier pipelined SUPERCHUNK loop (32 rows) ============
            // ---- prologue: superchunk 0 ----
            uint4 pxL = *(const uint4*)(gsrc + (size_t)s_rns[rsoff + min(r16, Pr - 1)] * 128);
            uint4 pxU = *(const uint4*)(gsrc + (size_t)s_rns[rsoff + min(16 + r16, Pr - 1)] * 128);
            *(uint4*)(s_Xh[0] + r16 * WROW + (c8 << 3)) = pxL;
            *(uint4*)(s_Xh[0] + (16 + r16) * WROW + (c8 << 3)) = pxU;
            float zredCL = gate(pxL);
            float zredCU = gate(pxU);
            if (Pr > 32) {                               // prefetch superchunk 1
                pxL = *(const uint4*)(gsrc + (size_t)s_rns[rsoff + min(32 + r16, Pr - 1)] * 128);
                pxU = *(const uint4*)(gsrc + (size_t)s_rns[rsoff + min(48 + r16, Pr - 1)] * 128);
            }
            bar_lds();                                   // publish Xh[0]

            floatx4 accmPL = {0, 0, 0, 0}, accmPU = {0, 0, 0, 0};
            float nsvPL[4] = {0, 0, 0, 0}, nsvPU[4] = {0, 0, 0, 0};
            int   nrPL[4] = {0, 0, 0, 0}, nrPU[4] = {0, 0, 0, 0};
            int PcPL = 0, PcPU = 0, sbP = 0;

            for (int c0 = 0; c0 < Pr; c0 += 32) {
                const int k = c0 >> 5;
                const int cur = k & 1, nxt = cur ^ 1;
                const int remn = Pr - c0;
                const bool fullU = remn >= 32;
                const int PcL = (remn >= 16) ? 16 : remn;
                const int PcU = fullU ? 16 : (remn > 16 ? remn - 16 : 0);
                const bool hasnext = remn > 32;
                // stage superchunk k+1 from px regs; gate-reduce it
                float zredNL = 0.0f, zredNU = 0.0f;
                if (hasnext) {
                    *(uint4*)(s_Xh[nxt] + r16 * WROW + (c8 << 3)) = pxL;
                    *(uint4*)(s_Xh[nxt] + (16 + r16) * WROW + (c8 << 3)) = pxU;
                    zredNL = gate(pxL);
                    zredNU = gate(pxU);
                }
                // prefetch superchunk k+2
                if (remn > 64) {
                    pxL = *(const uint4*)(gsrc + (size_t)s_rns[rsoff + min(c0 + 64 + r16, Pr - 1)] * 128);
                    pxU = *(const uint4*)(gsrc + (size_t)s_rns[rsoff + min(c0 + 80 + r16, Pr - 1)] * 128);
                }
                // current superchunk row ids
                int nrL[4], nrU[4];
                if (fullU) {
#pragma unroll
                    for (int i = 0; i < 4; ++i) {
                        nrL[i] = (int)s_rnode[c0 + q4 + i];
                        nrU[i] = (int)s_rnode[c0 + 16 + q4 + i];
                    }
                } else {
#pragma unroll
                    for (int i = 0; i < 4; ++i) {
                        nrL[i] = (int)s_rnode[min(c0 + q4 + i, Pr - 1)];
                        nrU[i] = (int)s_rnode[min(c0 + 16 + q4 + i, Pr - 1)];
                    }
                }
                // F: phase2 MFMA for superchunk k-1 (both halves; independent chains)
                if (c0 > 0) {
                    {
                        const _Float16* nrow = s_NSh[nxt] + lm * NROW + (quad << 3);
#pragma unroll
                        for (int c = 0; c < 4; ++c)
                            accmPL = __builtin_amdgcn_mfma_f32_16x16x32_f16(
                                *(const half8*)(nrow + (c << 5)), wbm[c], accmPL, 0, 0, 0);
                    }
                    {
                        const _Float16* nrow = s_NSh[nxt] + (16 + lm) * NROW + (quad << 3);
#pragma unroll
                        for (int c = 0; c < 4; ++c)
                            accmPU = __builtin_amdgcn_mfma_f32_16x16x32_f16(
                                *(const half8*)(nrow + (c << 5)), wbm[c], accmPU, 0, 0, 0);
                    }
                    float naL[4], naU[4];
#pragma unroll
                    for (int i = 0; i < 4; ++i) {
                        naL[i] = s_rna[nxt][q4 + i];
                        naU[i] = s_rna[nxt][16 + q4 + i];
                    }
                    if (PcPU == 16) {                    // fully-full previous superchunk
#pragma unroll
                        for (int i = 0; i < 4; ++i) {
                            nmbuf_h[(size_t)(sbP + q4 + i) * M + colw] =
                                (_Float16)(accmPL[i] + nmb_c);
                            nmbuf_h[(size_t)(sbP + 16 + q4 + i) * M + colw] =
                                (_Float16)(accmPU[i] + nmb_c);
                        }
#pragma unroll
                        for (int i = 0; i < 4; ++i) {
                            atomicAdd(finalv + (size_t)nrPL[i] * H + colw, nsvPL[i] * naL[i]);
                            atomicAdd(finalv + (size_t)nrPU[i] * H + colw, nsvPU[i] * naU[i]);
                        }
                    } else {
#pragma unroll
                        for (int i = 0; i < 4; ++i) {
                            const int r = q4 + i;
                            if (r < PcPL) {
                                nmbuf_h[(size_t)(sbP + r) * M + colw] =
                                    (_Float16)(accmPL[i] + nmb_c);
                                atomicAdd(finalv + (size_t)nrPL[i] * H + colw,
                                          nsvPL[i] * naL[i]);
                            }
                            if (r < PcPU) {
                                nmbuf_h[(size_t)(sbP + 16 + r) * M + colw] =
                                    (_Float16)(accmPU[i] + nmb_c);
                                atomicAdd(finalv + (size_t)nrPU[i] * H + colw,
                                          nsvPU[i] * naU[i]);
                            }
                        }
                    }
                }
                // E: gate finalize superchunk k (1 thread per row; overlaps MFMA)
                if (sg == 0) {
                    if (r16 < PcL) {
                        const float z = zredCL + actb;
                        const float cnd = 1.0f / (1.0f + expf(-z));
                        const int nr = (int)s_rnode[c0 + r16];
                        const float ta = s_tact[nr];
                        const float na = (ta + cnd > 1.0f) ? (1.0f - ta) : cnd;
                        s_rna[cur][r16] = na;
                        s_tact[nr] = ta + na;
                    }
                    if (r16 < PcU) {
                        const float z = zredCU + actb;
                        const float cnd = 1.0f / (1.0f + expf(-z));
                        const int nr = (int)s_rnode[c0 + 16 + r16];
                        const float ta = s_tact[nr];
                        const float na = (ta + cnd > 1.0f) ? (1.0f - ta) : cnd;
                        s_rna[cur][16 + r16] = na;
                        s_tact[nr] = ta + na;
                    }
                }
                // D: phase1 MFMA superchunk k, L then U (independent chains)
                floatx4 accmL, accmU;
                float nsvL[4], nsvU[4];
                {
                    floatx4 accn = {0, 0, 0, 0}, accm = {0, 0, 0, 0};
                    const _Float16* xrow = s_Xh[cur] + lm * WROW + (quad << 3);
                    half8 a[8];
#pragma unroll
                    for (int c = 0; c < 8; ++c) a[c] = *(const half8*)(xrow + (c << 5));
#pragma unroll
                    for (int c = 0; c < 8; ++c)
                        accn = __builtin_amdgcn_mfma_f32_16x16x32_f16(a[c], wbn[c], accn, 0, 0, 0);
#pragma unroll
                    for (int c = 4; c < 8; ++c)
                        accm = __builtin_amdgcn_mfma_f32_16x16x32_f16(a[c], wbm[c], accm, 0, 0, 0);
#pragma unroll
                    for (int i = 0; i < 4; ++i) nsvL[i] = fmaxf(accn[i] + nsb_c, 0.0f);
                    accmL = accm;
                }
                {
                    floatx4 accn = {0, 0, 0, 0}, accm = {0, 0, 0, 0};
                    const _Float16* xrow = s_Xh[cur] + (16 + lm) * WROW + (quad << 3);
                    half8 a[8];
#pragma unroll
                    for (int c = 0; c < 8; ++c) a[c] = *(const half8*)(xrow + (c << 5));
#pragma unroll
                    for (int c = 0; c < 8; ++c)
                        accn = __builtin_amdgcn_mfma_f32_16x16x32_f16(a[c], wbn[c], accn, 0, 0, 0);
#pragma unroll
                    for (int c = 4; c < 8; ++c)
                        accm = __builtin_amdgcn_mfma_f32_16x16x32_f16(a[c], wbm[c], accm, 0, 0, 0);
#pragma unroll
                    for (int i = 0; i < 4; ++i) nsvU[i] = fmaxf(accn[i] + nsb_c, 0.0f);
                    accmU = accm;
                }
                if (fullU) {
#pragma unroll
                    for (int i = 0; i < 4; ++i) {
                        const int r = q4 + i;
                        s_NSh[cur][r * NROW + colw] = (_Float16)nsvL[i];
                        feats_h[(size_t)nrL[i] * H + colw] = (_Float16)nsvL[i];
                        s_NSh[cur][(16 + r) * NROW + colw] = (_Float16)nsvU[i];
                        feats_h[(size_t)nrU[i] * H + colw] = (_Float16)nsvU[i];
                    }
                } else {
#pragma unroll
                    for (int i = 0; i < 4; ++i) {
                        const int r = q4 + i;
                        if (r < PcL) {
                            s_NSh[cur][r * NROW + colw] = (_Float16)nsvL[i];
                            feats_h[(size_t)nrL[i] * H + colw] = (_Float16)nsvL[i];
                        }
                        if (r < PcU) {
                            s_NSh[cur][(16 + r) * NROW + colw] = (_Float16)nsvU[i];
                            feats_h[(size_t)nrU[i] * H + colw] = (_Float16)nsvU[i];
                        }
                    }
                }
                // rotate pipeline state
                accmPL = accmL; accmPU = accmU;
#pragma unroll
                for (int i = 0; i < 4; ++i) {
                    nsvPL[i] = nsvL[i]; nrPL[i] = nrL[i];
                    nsvPU[i] = nsvU[i]; nrPU[i] = nrU[i];
                }
                PcPL = PcL; PcPU = PcU; sbP = gbase + base + c0;
                zredCL = zredNL; zredCU = zredNU;
                bar_lds();               // publish Xh[nxt], NSh[cur], rna[cur]
            }
            // ---- epilogue: phase2 for last superchunk ----
            {
                const int pb = ((Pr - 1) >> 5) & 1;
                {
                    const _Float16* nrow = s_NSh[pb] + lm * NROW + (quad << 3);
#pragma unroll
                    for (int c = 0; c < 4; ++c)
                        accmPL = __builtin_amdgcn_mfma_f32_16x16x32_f16(
                            *(const half8*)(nrow + (c << 5)), wbm[c], accmPL, 0, 0, 0);
                }
                {
                    const _Float16* nrow = s_NSh[pb] + (16 + lm) * NROW + (quad << 3);
#pragma unroll
                    for (int c = 0; c < 4; ++c)
                        accmPU = __builtin_amdgcn_mfma_f32_16x16x32_f16(
                            *(const half8*)(nrow + (c << 5)), wbm[c], accmPU, 0, 0, 0);
                }
#pragma unroll
                for (int i = 0; i < 4; ++i) {
                    const int r = q4 + i;
                    if (r < PcPL) {
                        nmbuf_h[(size_t)(sbP + r) * M + colw] =
                            (_Float16)(accmPL[i] + nmb_c);
                        atomicAdd(finalv + (size_t)nrPL[i] * H + colw,
                                  nsvPL[i] * s_rna[pb][r]);
                    }
                    if (r < PcPU) {
                        nmbuf_h[(size_t)(sbP + 16 + r) * M + colw] =
                            (_Float16)(accmPU[i] + nmb_c);
                        atomicAdd(finalv + (size_t)nrPU[i] * H + colw,
                                  nsvPU[i] * s_rna[pb][16 + r]);
                    }
                }
            }
            base += Pr;
            bar_lds();             // R7 (LDS-only; vmcnt drained at next R1)
        }

        // -------- enqueue (queue order via two-class prefix over flags) --------
        const bool pfa = (s_flag[t] & 1) != 0;
        const bool pfb = (s_flag[t] & 2) != 0;
        const unsigned long long mfa = __ballot(pfa);
        const unsigned long long mfb = __ballot(pfb);
        if (lane == 0) { s_wc[wid] = __popcll(mfa); s_wd[wid] = __popcll(mfb); }
        bar_lds();                                       // B3
        int TA = 0, TB = 0, preA = 0, preB = 0;
#pragma unroll
        for (int w = 0; w < 8; ++w) {
            TA += s_wc[w]; TB += s_wd[w];
            preA += (w < wid) ? s_wc[w] : 0;
            preB += (w < wid) ? s_wd[w] : 0;
        }
        const int T = TA + TB;
        if (T > 0) {
            const unsigned long long below = (1ull << lane) - 1ull;
            if (pfa) s_order[preA + __popcll(mfa & below)] = (short)t;
            if (pfb) s_order[TA + preB + __popcll(mfb & below)] = (short)(NT + t);
            bar_lds();                                   // B4
            for (int idx = t; idx < T * DEG; idx += NT) {
                const int e = (int)s_order[idx >> 4];
                const unsigned v = s_enq[e];
                const int nd = (int)(v & 0xffffu);
                const unsigned slot = v >> 16;
                const int q = tail + idx;
                if (q < QCAP)
                    s_q[q] = (unsigned)neighbors[nd * DEG + (idx & 15)] | (slot << 16);
            }
        }
        tail += DEG * T;
        gbase += T;
        head += W;
        bar_lds();                                       // B5 (LDS-only): s_q visible
    }

    // drain outstanding finalv atomics / stores before readout
    __syncthreads();

    // ---- readout (g/lg overlaid on dead mark region) ----
    if (t < H) {
        float g0 = 0, g1 = 0, g2 = 0, g3 = 0;
        for (int n = 0; n < NN; n += 4) {
            g0 += finalv[(n + 0) * H + t];
            g1 += finalv[(n + 1) * H + t];
            g2 += finalv[(n + 2) * H + t];
            g3 += finalv[(n + 3) * H + t];
        }
        s_g[t] = (g0 + g1) + (g2 + g3);
    }
    __syncthreads();
    if (t < PP * OUTF) {
        const int pp = t / OUTF, o = t % OUTF;
        float acc = dec_b[pp * OUTF + o];
        for (int h = 0; h < H; ++h) acc += s_g[h] * dec_w[(pp * H + h) * OUTF + o];
        s_lg[t] = acc;
    }
    __syncthreads();
    if (t < PP * OUTF) {
        const int pp = t / OUTF;
        float mx = -INFINITY;
        for (int o = 0; o < OUTF; ++o) mx = fmaxf(mx, s_lg[pp * OUTF + o]);
        float s = 0.0f;
        for (int o = 0; o < OUTF; ++o) s += expf(s_lg[pp * OUTF + o] - mx);
        out[t] = s_lg[t] - (mx + logf(s));
    }
}

extern "C" void kernel_launch(void* const* d_in, const int* in_sizes, int n_in,
                              void* d_out, int out_size, void* d_ws, size_t ws_size,
                              hipStream_t stream) {
    const float* xa        = (const float*)d_in[0];
    const float* fm        = (const float*)d_in[1];
    const int*   neighbors = (const int*)  d_in[2];
    const int*   nstart_p  = (const int*)  d_in[3];
    const float* enc_w     = (const float*)d_in[4];
    const float* enc_b     = (const float*)d_in[5];
    const float* ns_w      = (const float*)d_in[6];
    const float* ns_b      = (const float*)d_in[7];
    const float* nm_w      = (const float*)d_in[8];
    const float* nm_b      = (const float*)d_in[9];
    const float* act_w     = (const float*)d_in[10];
    const float* act_b     = (const float*)d_in[11];
    const float* dec_w     = (const float*)d_in[12];
    const float* dec_b     = (const float*)d_in[13];
    float* out = (float*)d_out;

    char* w = (char*)d_ws;
    _Float16* feats_h = (_Float16*)w;                 w += (size_t)NN * H * 2;
    float*    finalv  = (float*)w;                    w += (size_t)NN * H * 4;
    _Float16* nmbuf_h = (_Float16*)w;                 w += (size_t)NSLOT * M * 2;
    _Float16* wnsB    = (_Float16*)w;                 w += (size_t)128 * WROW * 2;
    _Float16* wnmB    = (_Float16*)w;                 w += (size_t)128 * WROW * 2;
    unsigned int* qpack = (unsigned int*)w;           // unused (LDS queue)

    init_kernel<<<NN, 128, 0, stream>>>(xa, fm, enc_w, enc_b, nstart_p,
                                        feats_h, finalv, nmbuf_h);
    pack_kernel<<<132, 256, 0, stream>>>(ns_w, nm_w, wnsB, wnmB);
    seq_kernel<<<1, NT, 0, stream>>>(neighbors, ns_b, nm_b,
                                     act_w, act_b, dec_w, dec_b, nstart_p,
                                     wnsB, wnmB,
                                     feats_h, finalv, nmbuf_h, qpack, out);
}

// Round 9
// 529.777 us; speedup vs baseline: 1.0461x; 1.0461x over previous
//
#include <hip/hip_runtime.h>
#include <math.h>

#define NN 1000
#define INF_ 32
#define H 128
#define M 128
#define DEG 16
#define PP 2
#define OUTF 10
#define MAXM (10 * NN)        // scan length; head <= MAXM
#define QCAP (MAXM + DEG)     // only entries < MAXM are ever read
#define NSLOT (MAXM + 128)    // nmbuf rows: nstart + total procs
#define NT 512
#define WQ (2 * NT)           // window size: 2 queue entries per thread
#define WROW 264              // padded halves per X/weight row (256+8)
#define NROW 136              // padded halves per NSh row (128+8)

typedef _Float16 half8 __attribute__((ext_vector_type(8)));
typedef float floatx4 __attribute__((ext_vector_type(4)));

// LDS-only barrier: publishes LDS writes without draining global (vmcnt) queue.
__device__ __forceinline__ void bar_lds() {
    asm volatile("s_waitcnt lgkmcnt(0)\n\ts_barrier" ::: "memory");
}

__global__ __launch_bounds__(128)
void init_kernel(const float* __restrict__ xa, const float* __restrict__ fm,
                 const float* __restrict__ enc_w, const float* __restrict__ enc_b,
                 const int* __restrict__ nstart_p,
                 _Float16* __restrict__ feats_h, float* __restrict__ finalv,
                 _Float16* __restrict__ nmbuf_h) {
    int b = blockIdx.x, t = threadIdx.x;
    float acc = enc_b[t];
    const float* xr = xa + b * INF_;
#pragma unroll
    for (int k = 0; k < INF_; ++k) acc += xr[k] * enc_w[k * H + t];
    feats_h[b * H + t] = (_Float16)acc;     // same rounding point as before
    finalv[b * H + t] = 0.0f;
    if (b < nstart_p[0]) nmbuf_h[(size_t)b * M + t] = (_Float16)fm[b * M + t];
}

// Pack weights fp16 transposed [n][k] with +8 pad: wB[n*WROW+k] = w[k][n].
__global__ __launch_bounds__(256)
void pack_kernel(const float* __restrict__ ns_w, const float* __restrict__ nm_w,
                 _Float16* __restrict__ wnsB, _Float16* __restrict__ wnmB) {
    const int idx = blockIdx.x * 256 + threadIdx.x;   // 128*WROW
    if (idx >= 128 * WROW) return;
    const int n = idx / WROW, k = idx % WROW;
    wnsB[idx] = (k < 256) ? (_Float16)ns_w[k * H + n] : (_Float16)0.0f;
    wnmB[idx] = (k < 256) ? (_Float16)nm_w[k * M + n] : (_Float16)0.0f;
}

// Rank-decomposed sequential ACT loop; MFMA matvecs with REGISTER-RESIDENT
// weight B-fragments; LDS-only fine barriers; LDS message queue.
// R8 (VALU/L2-op diet on R7's superchunk pipeline):
//  - feats stores COALESCED: D writes only s_NSh (guard-free; garbage rows
//    never consumed); F/epilogue copies full fp16 rows NSh->feats_h as one
//    uint4 per thread (1 rowid ds_read vs 8; 2 full lines vs 4 partial).
//  - nr register rotation replaced by c0P carry + direct rowid reads in F.
__global__ __launch_bounds__(NT, 1)
void seq_kernel(const int* __restrict__ neighbors,
                const float* __restrict__ ns_b, const float* __restrict__ nm_b,
                const float* __restrict__ act_w, const float* __restrict__ act_b,
                const float* __restrict__ dec_w, const float* __restrict__ dec_b,
                const int* __restrict__ nstart_p,
                const _Float16* __restrict__ wnsB, const _Float16* __restrict__ wnmB,
                _Float16* __restrict__ feats_h, float* __restrict__ finalv,
                _Float16* __restrict__ nmbuf_h, unsigned int* __restrict__ qpack_unused,
                float* __restrict__ out) {
    __shared__ __align__(16) _Float16 s_Xh[2][32 * WROW];   // 33792 B
    __shared__ __align__(16) _Float16 s_NSh[2][32 * NROW];  // 17408 B
    __shared__ unsigned int s_q[QCAP];                      // 40064 B (LDS queue)
    __shared__ float s_tact[NN];                            // 4000 B
    __shared__ int   s_mark[NN];                            // 4000 B (order/readout overlay)
    __shared__ float s_actw[H + M];
    __shared__ float s_nsb[H];
    __shared__ float s_nmb[M];
    __shared__ float s_rna[2][32];
    __shared__ unsigned short s_rns[2 * WQ];                // [0]=node, [WQ]=slot, rank order
    __shared__ unsigned int  s_enq[WQ];                     // node|newslot<<16 per entry
    __shared__ unsigned char s_flag[NT];                    // bit0: entry t, bit1: entry 512+t
    __shared__ int s_wc[8], s_wd[8];
    __shared__ int s_cnt;

    unsigned short* const s_rnode = s_rns;
    short* s_order = (short*)s_mark;                     // overlay: mark[0..511] = 1024 shorts
    float* s_g  = (float*)(s_mark + 512);                // overlay: readout only
    float* s_lg = (float*)(s_mark + 512 + 128);

    const int t = threadIdx.x;
    const int lane = t & 63, wid = t >> 6;
    const int quad = lane >> 4, lm = lane & 15;
    const int q4 = quad << 2;
    const int colw = (wid << 4) + lm;                    // this thread's output col
    const int sg = t & 31;                               // gate sub-lane
    const int r16 = t >> 5, c8 = t & 31;                 // staging coords (16x32)
    const int rowc = t >> 4, c16 = t & 15;               // feats-copy coords (32x16)
    const int nstart = nstart_p[0];
    // loop-invariant staging source (feats row stride == nmbuf row stride == 128 halves)
    const int rsoff = (c8 < 16) ? 0 : WQ;
    const _Float16* const gsrc = (c8 < 16) ? (feats_h + c8 * 8)
                                           : (nmbuf_h + (c8 - 16) * 8);

    // ---- one-time: weight B-fragments into registers (loop-invariant) ----
    half8 wbn[8], wbm[8];
#pragma unroll
    for (int c = 0; c < 8; ++c) {
        wbn[c] = *(const half8*)(wnsB + (size_t)colw * WROW + (c << 5) + (quad << 3));
        wbm[c] = *(const half8*)(wnmB + (size_t)colw * WROW + (c << 5) + (quad << 3));
    }

    for (int i = t; i < NN; i += NT) { s_tact[i] = 0.0f; s_mark[i] = 0x7fffffff; }
    for (int i = t; i < nstart; i += NT) s_q[i] = (unsigned)i | ((unsigned)i << 16);
    if (t < H + M) s_actw[t] = act_w[t];
    if (t < H) { s_nsb[t] = ns_b[t]; s_nmb[t] = nm_b[t]; }
    const float actb = act_b[0];
    __syncthreads();
    const float nsb_c = s_nsb[colw];
    const float nmb_c = s_nmb[colw];
    float aw[8];
#pragma unroll
    for (int j = 0; j < 8; ++j) aw[j] = s_actw[sg * 8 + j];

    // gate partial from staging registers (bitwise == old LDS-read path)
    auto gate = [&](uint4 v) -> float {
        const half8 hv = *(const half8*)&v;
        float p = 0.0f;
#pragma unroll
        for (int j = 0; j < 8; ++j) p += (float)hv[j] * aw[j];
#pragma unroll
        for (int off = 16; off > 0; off >>= 1) p += __shfl_down(p, off, 32);
        return p;                                        // valid in sg==0
    };

    int head = 0, tail = nstart, gbase = nstart;
    for (;;) {
        const int lim = min(tail, MAXM);
        if (head >= lim) break;
        const int W = min(WQ, lim - head);

        // ---- classify both entries; clear flags; repair order-overlaid mark ----
        int nodeA = 0, slotA = 0; bool remA = false;
        int nodeB = 0, slotB = 0; bool remB = false;
        if (t < W) {
            const unsigned v = s_q[head + t];
            nodeA = (int)(v & 0xffffu);
            slotA = (int)(v >> 16);
            remA = (s_tact[nodeA] <= 1.0f - 1e-7f);
        }
        if (NT + t < W) {
            const unsigned v = s_q[head + NT + t];
            nodeB = (int)(v & 0xffffu);
            slotB = (int)(v >> 16);
            remB = (s_tact[nodeB] <= 1.0f - 1e-7f);
        }
        s_flag[t] = 0;
        s_mark[t] = 0x7fffffff;                          // repair overlay (t<512 region)
        bar_lds();                                       // B1

        // ---------------- rank rounds ----------------
        int base = 0;
        for (;;) {
            const bool rem2a = remA && (s_tact[nodeA] <= 1.0f - 1e-7f);
            const bool rem2b = remB && (s_tact[nodeB] <= 1.0f - 1e-7f);
            if (rem2a) atomicMin(&s_mark[nodeA], t);
            if (rem2b) atomicMin(&s_mark[nodeB], NT + t);
            if (t == 0) s_cnt = 0;
            // drain prior rounds' global stores here (overlapped by the work
            // above); the following barrier then publishes them block-wide.
            asm volatile("s_waitcnt vmcnt(0)" ::: "memory");
            bar_lds();                                   // R1
            const bool winA = rem2a && (s_mark[nodeA] == t);
            const bool winB = rem2b && (s_mark[nodeB] == NT + t);
            const unsigned long long ma = __ballot(winA);
            const unsigned long long mb = __ballot(winB);
            const int ca = __popcll(ma), cb = __popcll(mb);
            int wbase = 0;
            if (lane == 0 && (ca + cb)) wbase = atomicAdd(&s_cnt, ca + cb);
            wbase = __shfl(wbase, 0, 64);
            const unsigned long long below = (1ull << lane) - 1ull;
            if (winA) {
                const int wrank = wbase + __popcll(ma & below);
                s_rns[wrank] = (unsigned short)nodeA;
                s_rns[WQ + wrank] = (unsigned short)slotA;
                s_enq[t] = (unsigned)nodeA | ((unsigned)(gbase + base + wrank) << 16);
                s_flag[t] |= 1;
            }
            if (winB) {
                const int wrank = wbase + ca + __popcll(mb & below);
                s_rns[wrank] = (unsigned short)nodeB;
                s_rns[WQ + wrank] = (unsigned short)slotB;
                s_enq[NT + t] = (unsigned)nodeB | ((unsigned)(gbase + base + wrank) << 16);
                s_flag[t] |= 2;
            }
            remA = rem2a && !winA;
            remB = rem2b && !winB;
            bar_lds();                                   // R3: rnode/rslot/cnt ready
            if (rem2a) s_mark[nodeA] = 0x7fffffff;       // reset (barrier-separated)
            if (rem2b) s_mark[nodeB] = 0x7fffffff;
            const int Pr = s_cnt;
            if (Pr == 0) break;

            // ============ single-barrier pipelined SUPERCHUNK loop (32 rows) ============
            // ---- prologue: superchunk 0 ----
            uint4 pxL = *(const uint4*)(gsrc + (size_t)s_rns[rsoff + min(r16, Pr - 1)] * 128);
            uint4 pxU = *(const uint4*)(gsrc + (size_t)s_rns[rsoff + min(16 + r16, Pr - 1)] * 128);
            *(uint4*)(s_Xh[0] + r16 * WROW + (c8 << 3)) = pxL;
            *(uint4*)(s_Xh[0] + (16 + r16) * WROW + (c8 << 3)) = pxU;
            float zredCL = gate(pxL);
            float zredCU = gate(pxU);
            if (Pr > 32) {                               // prefetch superchunk 1
                pxL = *(const uint4*)(gsrc + (size_t)s_rns[rsoff + min(32 + r16, Pr - 1)] * 128);
                pxU = *(const uint4*)(gsrc + (size_t)s_rns[rsoff + min(48 + r16, Pr - 1)] * 128);
            }
            bar_lds();                                   // publish Xh[0]

            floatx4 accmPL = {0, 0, 0, 0}, accmPU = {0, 0, 0, 0};
            float nsvPL[4] = {0, 0, 0, 0}, nsvPU[4] = {0, 0, 0, 0};
            int PcPL = 0, PcPU = 0, sbP = 0, c0P = 0;

            // F phase for superchunk at window-row base c0P (parity pb):
            // phase2 MFMA + nmbuf scatter + finalv atomics + COALESCED feats copy.
            auto phase2 = [&](int pb) {
                {
                    const _Float16* nrow = s_NSh[pb] + lm * NROW + (quad << 3);
#pragma unroll
                    for (int c = 0; c < 4; ++c)
                        accmPL = __builtin_amdgcn_mfma_f32_16x16x32_f16(
                            *(const half8*)(nrow + (c << 5)), wbm[c], accmPL, 0, 0, 0);
                }
                {
                    const _Float16* nrow = s_NSh[pb] + (16 + lm) * NROW + (quad << 3);
#pragma unroll
                    for (int c = 0; c < 4; ++c)
                        accmPU = __builtin_amdgcn_mfma_f32_16x16x32_f16(
                            *(const half8*)(nrow + (c << 5)), wbm[c], accmPU, 0, 0, 0);
                }
                float naL[4], naU[4];
                int nrL[4], nrU[4];
#pragma unroll
                for (int i = 0; i < 4; ++i) {
                    naL[i] = s_rna[pb][q4 + i];
                    naU[i] = s_rna[pb][16 + q4 + i];
                    nrL[i] = (int)s_rnode[c0P + q4 + i];
                    nrU[i] = (int)s_rnode[c0P + 16 + q4 + i];
                }
                if (PcPU == 16) {                        // fully-full superchunk
#pragma unroll
                    for (int i = 0; i < 4; ++i) {
                        nmbuf_h[(size_t)(sbP + q4 + i) * M + colw] =
                            (_Float16)(accmPL[i] + nmb_c);
                        nmbuf_h[(size_t)(sbP + 16 + q4 + i) * M + colw] =
                            (_Float16)(accmPU[i] + nmb_c);
                    }
#pragma unroll
                    for (int i = 0; i < 4; ++i) {
                        atomicAdd(finalv + (size_t)nrL[i] * H + colw, nsvPL[i] * naL[i]);
                        atomicAdd(finalv + (size_t)nrU[i] * H + colw, nsvPU[i] * naU[i]);
                    }
                } else {
#pragma unroll
                    for (int i = 0; i < 4; ++i) {
                        const int r = q4 + i;
                        if (r < PcPL) {
                            nmbuf_h[(size_t)(sbP + r) * M + colw] =
                                (_Float16)(accmPL[i] + nmb_c);
                            atomicAdd(finalv + (size_t)nrL[i] * H + colw,
                                      nsvPL[i] * naL[i]);
                        }
                        if (r < PcPU) {
                            nmbuf_h[(size_t)(sbP + 16 + r) * M + colw] =
                                (_Float16)(accmPU[i] + nmb_c);
                            atomicAdd(finalv + (size_t)nrU[i] * H + colw,
                                      nsvPU[i] * naU[i]);
                        }
                    }
                }
                // coalesced feats copy: one full fp16 row per 16 threads
                if (rowc < PcPL || (unsigned)(rowc - 16) < (unsigned)PcPU) {
                    const int nrr = (int)s_rnode[c0P + rowc];
                    const uint4 v = *(const uint4*)(s_NSh[pb] + rowc * NROW + (c16 << 3));
                    *(uint4*)(feats_h + (size_t)nrr * H + (c16 << 3)) = v;
                }
            };

            for (int c0 = 0; c0 < Pr; c0 += 32) {
                const int k = c0 >> 5;
                const int cur = k & 1, nxt = cur ^ 1;
                const int remn = Pr - c0;
                const int PcL = (remn >= 16) ? 16 : remn;
                const int PcU = (remn >= 32) ? 16 : (remn > 16 ? remn - 16 : 0);
                const bool hasnext = remn > 32;
                // stage superchunk k+1 from px regs; gate-reduce it
                float zredNL = 0.0f, zredNU = 0.0f;
                if (hasnext) {
                    *(uint4*)(s_Xh[nxt] + r16 * WROW + (c8 << 3)) = pxL;
                    *(uint4*)(s_Xh[nxt] + (16 + r16) * WROW + (c8 << 3)) = pxU;
                    zredNL = gate(pxL);
                    zredNU = gate(pxU);
                }
                // prefetch superchunk k+2
                if (remn > 64) {
                    pxL = *(const uint4*)(gsrc + (size_t)s_rns[rsoff + min(c0 + 64 + r16, Pr - 1)] * 128);
                    pxU = *(const uint4*)(gsrc + (size_t)s_rns[rsoff + min(c0 + 80 + r16, Pr - 1)] * 128);
                }
                // F: superchunk k-1 (NSh[nxt] holds parity (k-1)&1 == nxt)
                if (c0 > 0) phase2(nxt);
                // E: gate finalize superchunk k (1 thread per row; overlaps MFMA)
                if (sg == 0) {
                    if (r16 < PcL) {
                        const float z = zredCL + actb;
                        const float cnd = 1.0f / (1.0f + expf(-z));
                        const int nr = (int)s_rnode[c0 + r16];
                        const float ta = s_tact[nr];
                        const float na = (ta + cnd > 1.0f) ? (1.0f - ta) : cnd;
                        s_rna[cur][r16] = na;
                        s_tact[nr] = ta + na;
                    }
                    if (r16 < PcU) {
                        const float z = zredCU + actb;
                        const float cnd = 1.0f / (1.0f + expf(-z));
                        const int nr = (int)s_rnode[c0 + 16 + r16];
                        const float ta = s_tact[nr];
                        const float na = (ta + cnd > 1.0f) ? (1.0f - ta) : cnd;
                        s_rna[cur][16 + r16] = na;
                        s_tact[nr] = ta + na;
                    }
                }
                // D: phase1 MFMA superchunk k, L then U (guard-free; NSh only)
                floatx4 accmL, accmU;
                float nsvL[4], nsvU[4];
                {
                    floatx4 accn = {0, 0, 0, 0}, accm = {0, 0, 0, 0};
                    const _Float16* xrow = s_Xh[cur] + lm * WROW + (quad << 3);
                    half8 a[8];
#pragma unroll
                    for (int c = 0; c < 8; ++c) a[c] = *(const half8*)(xrow + (c << 5));
#pragma unroll
                    for (int c = 0; c < 8; ++c)
                        accn = __builtin_amdgcn_mfma_f32_16x16x32_f16(a[c], wbn[c], accn, 0, 0, 0);
#pragma unroll
                    for (int c = 4; c < 8; ++c)
                        accm = __builtin_amdgcn_mfma_f32_16x16x32_f16(a[c], wbm[c], accm, 0, 0, 0);
#pragma unroll
                    for (int i = 0; i < 4; ++i) {
                        nsvL[i] = fmaxf(accn[i] + nsb_c, 0.0f);
                        s_NSh[cur][(q4 + i) * NROW + colw] = (_Float16)nsvL[i];
                    }
                    accmL = accm;
                }
                {
                    floatx4 accn = {0, 0, 0, 0}, accm = {0, 0, 0, 0};
                    const _Float16* xrow = s_Xh[cur] + (16 + lm) * WROW + (quad << 3);
                    half8 a[8];
#pragma unroll
                    for (int c = 0; c < 8; ++c) a[c] = *(const half8*)(xrow + (c << 5));
#pragma unroll
                    for (int c = 0; c < 8; ++c)
                        accn = __builtin_amdgcn_mfma_f32_16x16x32_f16(a[c], wbn[c], accn, 0, 0, 0);
#pragma unroll
                    for (int c = 4; c < 8; ++c)
                        accm = __builtin_amdgcn_mfma_f32_16x16x32_f16(a[c], wbm[c], accm, 0, 0, 0);
#pragma unroll
                    for (int i = 0; i < 4; ++i) {
                        nsvU[i] = fmaxf(accn[i] + nsb_c, 0.0f);
                        s_NSh[cur][(16 + q4 + i) * NROW + colw] = (_Float16)nsvU[i];
                    }
                    accmU = accm;
                }
                // rotate pipeline state
                accmPL = accmL; accmPU = accmU;
#pragma unroll
                for (int i = 0; i < 4; ++i) { nsvPL[i] = nsvL[i]; nsvPU[i] = nsvU[i]; }
                PcPL = PcL; PcPU = PcU; sbP = gbase + base + c0; c0P = c0;
                zredCL = zredNL; zredCU = zredNU;
                bar_lds();               // publish Xh[nxt], NSh[cur], rna[cur]
            }
            // ---- epilogue: F for last superchunk (parity of c0P) ----
            phase2((c0P >> 5) & 1);
            base += Pr;
            bar_lds();             // R7 (LDS-only; vmcnt drained at next R1)
        }

        // -------- enqueue (queue order via two-class prefix over flags) --------
        const bool pfa = (s_flag[t] & 1) != 0;
        const bool pfb = (s_flag[t] & 2) != 0;
        const unsigned long long mfa = __ballot(pfa);
        const unsigned long long mfb = __ballot(pfb);
        if (lane == 0) { s_wc[wid] = __popcll(mfa); s_wd[wid] = __popcll(mfb); }
        bar_lds();                                       // B3
        int TA = 0, TB = 0, preA = 0, preB = 0;
#pragma unroll
        for (int w = 0; w < 8; ++w) {
            TA += s_wc[w]; TB += s_wd[w];
            preA += (w < wid) ? s_wc[w] : 0;
            preB += (w < wid) ? s_wd[w] : 0;
        }
        const int T = TA + TB;
        if (T > 0) {
            const unsigned long long below = (1ull << lane) - 1ull;
            if (pfa) s_order[preA + __popcll(mfa & below)] = (short)t;
            if (pfb) s_order[TA + preB + __popcll(mfb & below)] = (short)(NT + t);
            bar_lds();                                   // B4
            for (int idx = t; idx < T * DEG; idx += NT) {
                const int e = (int)s_order[idx >> 4];
                const unsigned v = s_enq[e];
                const int nd = (int)(v & 0xffffu);
                const unsigned slot = v >> 16;
                const int q = tail + idx;
                if (q < QCAP)
                    s_q[q] = (unsigned)neighbors[nd * DEG + (idx & 15)] | (slot << 16);
            }
        }
        tail += DEG * T;
        gbase += T;
        head += W;
        bar_lds();                                       // B5 (LDS-only): s_q visible
    }

    // drain outstanding finalv atomics / stores before readout
    __syncthreads();

    // ---- readout (g/lg overlaid on dead mark region) ----
    if (t < H) {
        float g0 = 0, g1 = 0, g2 = 0, g3 = 0;
        for (int n = 0; n < NN; n += 4) {
            g0 += finalv[(n + 0) * H + t];
            g1 += finalv[(n + 1) * H + t];
            g2 += finalv[(n + 2) * H + t];
            g3 += finalv[(n + 3) * H + t];
        }
        s_g[t] = (g0 + g1) + (g2 + g3);
    }
    __syncthreads();
    if (t < PP * OUTF) {
        const int pp = t / OUTF, o = t % OUTF;
        float acc = dec_b[pp * OUTF + o];
        for (int h = 0; h < H; ++h) acc += s_g[h] * dec_w[(pp * H + h) * OUTF + o];
        s_lg[t] = acc;
    }
    __syncthreads();
    if (t < PP * OUTF) {
        const int pp = t / OUTF;
        float mx = -INFINITY;
        for (int o = 0; o < OUTF; ++o) mx = fmaxf(mx, s_lg[pp * OUTF + o]);
        float s = 0.0f;
        for (int o = 0; o < OUTF; ++o) s += expf(s_lg[pp * OUTF + o] - mx);
        out[t] = s_lg[t] - (mx + logf(s));
    }
}

extern "C" void kernel_launch(void* const* d_in, const int* in_sizes, int n_in,
                              void* d_out, int out_size, void* d_ws, size_t ws_size,
                              hipStream_t stream) {
    const float* xa        = (const float*)d_in[0];
    const float* fm        = (const float*)d_in[1];
    const int*   neighbors = (const int*)  d_in[2];
    const int*   nstart_p  = (const int*)  d_in[3];
    const float* enc_w     = (const float*)d_in[4];
    const float* enc_b     = (const float*)d_in[5];
    const float* ns_w      = (const float*)d_in[6];
    const float* ns_b      = (const float*)d_in[7];
    const float* nm_w      = (const float*)d_in[8];
    const float* nm_b      = (const float*)d_in[9];
    const float* act_w     = (const float*)d_in[10];
    const float* act_b     = (const float*)d_in[11];
    const float* dec_w     = (const float*)d_in[12];
    const float* dec_b     = (const float*)d_in[13];
    float* out = (float*)d_out;

    char* w = (char*)d_ws;
    _Float16* feats_h = (_Float16*)w;                 w += (size_t)NN * H * 2;
    float*    finalv  = (float*)w;                    w += (size_t)NN * H * 4;
    _Float16* nmbuf_h = (_Float16*)w;                 w += (size_t)NSLOT * M * 2;
    _Float16* wnsB    = (_Float16*)w;                 w += (size_t)128 * WROW * 2;
    _Float16* wnmB    = (_Float16*)w;                 w += (size_t)128 * WROW * 2;
    unsigned int* qpack = (unsigned int*)w;           // unused (LDS queue)

    init_kernel<<<NN, 128, 0, stream>>>(xa, fm, enc_w, enc_b, nstart_p,
                                        feats_h, finalv, nmbuf_h);
    pack_kernel<<<132, 256, 0, stream>>>(ns_w, nm_w, wnsB, wnmB);
    seq_kernel<<<1, NT, 0, stream>>>(neighbors, ns_b, nm_b,
                                     act_w, act_b, dec_w, dec_b, nstart_p,
                                     wnsB, wnmB,
                                     feats_h, finalv, nmbuf_h, qpack, out);
}

// Round 10
// 524.843 us; speedup vs baseline: 1.0559x; 1.0094x over previous
//
#include <hip/hip_runtime.h>
#include <math.h>

#define NN 1000
#define INF_ 32
#define H 128
#define M 128
#define DEG 16
#define PP 2
#define OUTF 10
#define MAXM (10 * NN)        // scan length; head <= MAXM
#define QCAP (MAXM + DEG)     // only entries < MAXM are ever read
#define NSLOT (MAXM + 128)    // nmbuf rows: nstart + total procs
#define NT 512
#define WQ (2 * NT)           // window size: 2 queue entries per thread
#define WROW 264              // padded halves per X/weight row (256+8)
#define NROW 136              // padded halves per NSh row (128+8)

typedef _Float16 half8 __attribute__((ext_vector_type(8)));
typedef float floatx4 __attribute__((ext_vector_type(4)));

// LDS-only barrier: publishes LDS writes without draining global (vmcnt) queue.
__device__ __forceinline__ void bar_lds() {
    asm volatile("s_waitcnt lgkmcnt(0)\n\ts_barrier" ::: "memory");
}

__global__ __launch_bounds__(128)
void init_kernel(const float* __restrict__ xa, const float* __restrict__ fm,
                 const float* __restrict__ enc_w, const float* __restrict__ enc_b,
                 const int* __restrict__ nstart_p,
                 _Float16* __restrict__ feats_h, float* __restrict__ finalv,
                 _Float16* __restrict__ nmbuf_h) {
    int b = blockIdx.x, t = threadIdx.x;
    float acc = enc_b[t];
    const float* xr = xa + b * INF_;
#pragma unroll
    for (int k = 0; k < INF_; ++k) acc += xr[k] * enc_w[k * H + t];
    feats_h[b * H + t] = (_Float16)acc;     // same rounding point as before
    finalv[b * H + t] = 0.0f;
    if (b < nstart_p[0]) nmbuf_h[(size_t)b * M + t] = (_Float16)fm[b * M + t];
}

// Pack weights fp16 transposed [n][k] with +8 pad: wB[n*WROW+k] = w[k][n].
__global__ __launch_bounds__(256)
void pack_kernel(const float* __restrict__ ns_w, const float* __restrict__ nm_w,
                 _Float16* __restrict__ wnsB, _Float16* __restrict__ wnmB) {
    const int idx = blockIdx.x * 256 + threadIdx.x;   // 128*WROW
    if (idx >= 128 * WROW) return;
    const int n = idx / WROW, k = idx % WROW;
    wnsB[idx] = (k < 256) ? (_Float16)ns_w[k * H + n] : (_Float16)0.0f;
    wnmB[idx] = (k < 256) ? (_Float16)nm_w[k * M + n] : (_Float16)0.0f;
}

// Rank-decomposed sequential ACT loop; MFMA matvecs with REGISTER-RESIDENT
// weight B-fragments; LDS-only fine barriers; LDS message queue.
// R9 (latency-exposure diet on R8):
//  - neighbors table in LDS as u16 (32KB; ids<1000 are exact): the enqueue
//    section's serial ds_read->global-load->store chain becomes all-LDS.
//  - R7 end-of-round barrier deleted: epilogue LDS reads are ordered before
//    each wave's R1 barrier; next round's s_rns writes happen after it.
__global__ __launch_bounds__(NT, 1)
void seq_kernel(const int* __restrict__ neighbors,
                const float* __restrict__ ns_b, const float* __restrict__ nm_b,
                const float* __restrict__ act_w, const float* __restrict__ act_b,
                const float* __restrict__ dec_w, const float* __restrict__ dec_b,
                const int* __restrict__ nstart_p,
                const _Float16* __restrict__ wnsB, const _Float16* __restrict__ wnmB,
                _Float16* __restrict__ feats_h, float* __restrict__ finalv,
                _Float16* __restrict__ nmbuf_h, unsigned int* __restrict__ qpack_unused,
                float* __restrict__ out) {
    __shared__ __align__(16) _Float16 s_Xh[2][32 * WROW];   // 33792 B
    __shared__ __align__(16) _Float16 s_NSh[2][32 * NROW];  // 17408 B
    __shared__ unsigned int s_q[QCAP];                      // 40064 B (LDS queue)
    __shared__ unsigned short s_nb[NN * DEG];               // 32000 B (neighbors u16)
    __shared__ float s_tact[NN];                            // 4000 B
    __shared__ int   s_mark[NN];                            // 4000 B (order/readout overlay)
    __shared__ float s_actw[H + M];
    __shared__ float s_nsb[H];
    __shared__ float s_nmb[M];
    __shared__ float s_rna[2][32];
    __shared__ unsigned short s_rns[2 * WQ];                // [0]=node, [WQ]=slot, rank order
    __shared__ unsigned int  s_enq[WQ];                     // node|newslot<<16 per entry
    __shared__ unsigned char s_flag[NT];                    // bit0: entry t, bit1: entry 512+t
    __shared__ int s_wc[8], s_wd[8];
    __shared__ int s_cnt;

    unsigned short* const s_rnode = s_rns;
    short* s_order = (short*)s_mark;                     // overlay: mark[0..511] = 1024 shorts
    float* s_g  = (float*)(s_mark + 512);                // overlay: readout only
    float* s_lg = (float*)(s_mark + 512 + 128);

    const int t = threadIdx.x;
    const int lane = t & 63, wid = t >> 6;
    const int quad = lane >> 4, lm = lane & 15;
    const int q4 = quad << 2;
    const int colw = (wid << 4) + lm;                    // this thread's output col
    const int sg = t & 31;                               // gate sub-lane
    const int r16 = t >> 5, c8 = t & 31;                 // staging coords (16x32)
    const int rowc = t >> 4, c16 = t & 15;               // feats-copy coords (32x16)
    const int nstart = nstart_p[0];
    // loop-invariant staging source (feats row stride == nmbuf row stride == 128 halves)
    const int rsoff = (c8 < 16) ? 0 : WQ;
    const _Float16* const gsrc = (c8 < 16) ? (feats_h + c8 * 8)
                                           : (nmbuf_h + (c8 - 16) * 8);

    // ---- one-time: weight B-fragments into registers (loop-invariant) ----
    half8 wbn[8], wbm[8];
#pragma unroll
    for (int c = 0; c < 8; ++c) {
        wbn[c] = *(const half8*)(wnsB + (size_t)colw * WROW + (c << 5) + (quad << 3));
        wbm[c] = *(const half8*)(wnmB + (size_t)colw * WROW + (c << 5) + (quad << 3));
    }

    for (int i = t; i < NN; i += NT) { s_tact[i] = 0.0f; s_mark[i] = 0x7fffffff; }
    for (int i = t; i < nstart; i += NT) s_q[i] = (unsigned)i | ((unsigned)i << 16);
    for (int i = t; i < NN * DEG; i += NT) s_nb[i] = (unsigned short)neighbors[i];
    if (t < H + M) s_actw[t] = act_w[t];
    if (t < H) { s_nsb[t] = ns_b[t]; s_nmb[t] = nm_b[t]; }
    const float actb = act_b[0];
    __syncthreads();
    const float nsb_c = s_nsb[colw];
    const float nmb_c = s_nmb[colw];
    float aw[8];
#pragma unroll
    for (int j = 0; j < 8; ++j) aw[j] = s_actw[sg * 8 + j];

    // gate partial from staging registers (bitwise == old LDS-read path)
    auto gate = [&](uint4 v) -> float {
        const half8 hv = *(const half8*)&v;
        float p = 0.0f;
#pragma unroll
        for (int j = 0; j < 8; ++j) p += (float)hv[j] * aw[j];
#pragma unroll
        for (int off = 16; off > 0; off >>= 1) p += __shfl_down(p, off, 32);
        return p;                                        // valid in sg==0
    };

    int head = 0, tail = nstart, gbase = nstart;
    for (;;) {
        const int lim = min(tail, MAXM);
        if (head >= lim) break;
        const int W = min(WQ, lim - head);

        // ---- classify both entries; clear flags; repair order-overlaid mark ----
        int nodeA = 0, slotA = 0; bool remA = false;
        int nodeB = 0, slotB = 0; bool remB = false;
        if (t < W) {
            const unsigned v = s_q[head + t];
            nodeA = (int)(v & 0xffffu);
            slotA = (int)(v >> 16);
            remA = (s_tact[nodeA] <= 1.0f - 1e-7f);
        }
        if (NT + t < W) {
            const unsigned v = s_q[head + NT + t];
            nodeB = (int)(v & 0xffffu);
            slotB = (int)(v >> 16);
            remB = (s_tact[nodeB] <= 1.0f - 1e-7f);
        }
        s_flag[t] = 0;
        s_mark[t] = 0x7fffffff;                          // repair overlay (t<512 region)
        bar_lds();                                       // B1

        // ---------------- rank rounds ----------------
        int base = 0;
        for (;;) {
            const bool rem2a = remA && (s_tact[nodeA] <= 1.0f - 1e-7f);
            const bool rem2b = remB && (s_tact[nodeB] <= 1.0f - 1e-7f);
            if (rem2a) atomicMin(&s_mark[nodeA], t);
            if (rem2b) atomicMin(&s_mark[nodeB], NT + t);
            if (t == 0) s_cnt = 0;
            // drain prior rounds' global stores here (overlapped by the work
            // above); the following barrier then publishes them block-wide.
            asm volatile("s_waitcnt vmcnt(0)" ::: "memory");
            bar_lds();                                   // R1
            const bool winA = rem2a && (s_mark[nodeA] == t);
            const bool winB = rem2b && (s_mark[nodeB] == NT + t);
            const unsigned long long ma = __ballot(winA);
            const unsigned long long mb = __ballot(winB);
            const int ca = __popcll(ma), cb = __popcll(mb);
            int wbase = 0;
            if (lane == 0 && (ca + cb)) wbase = atomicAdd(&s_cnt, ca + cb);
            wbase = __shfl(wbase, 0, 64);
            const unsigned long long below = (1ull << lane) - 1ull;
            if (winA) {
                const int wrank = wbase + __popcll(ma & below);
                s_rns[wrank] = (unsigned short)nodeA;
                s_rns[WQ + wrank] = (unsigned short)slotA;
                s_enq[t] = (unsigned)nodeA | ((unsigned)(gbase + base + wrank) << 16);
                s_flag[t] |= 1;
            }
            if (winB) {
                const int wrank = wbase + ca + __popcll(mb & below);
                s_rns[wrank] = (unsigned short)nodeB;
                s_rns[WQ + wrank] = (unsigned short)slotB;
                s_enq[NT + t] = (unsigned)nodeB | ((unsigned)(gbase + base + wrank) << 16);
                s_flag[t] |= 2;
            }
            remA = rem2a && !winA;
            remB = rem2b && !winB;
            bar_lds();                                   // R3: rnode/rslot/cnt ready
            if (rem2a) s_mark[nodeA] = 0x7fffffff;       // reset (barrier-separated)
            if (rem2b) s_mark[nodeB] = 0x7fffffff;
            const int Pr = s_cnt;
            if (Pr == 0) break;

            // ============ single-barrier pipelined SUPERCHUNK loop (32 rows) ============
            // ---- prologue: superchunk 0 ----
            uint4 pxL = *(const uint4*)(gsrc + (size_t)s_rns[rsoff + min(r16, Pr - 1)] * 128);
            uint4 pxU = *(const uint4*)(gsrc + (size_t)s_rns[rsoff + min(16 + r16, Pr - 1)] * 128);
            *(uint4*)(s_Xh[0] + r16 * WROW + (c8 << 3)) = pxL;
            *(uint4*)(s_Xh[0] + (16 + r16) * WROW + (c8 << 3)) = pxU;
            float zredCL = gate(pxL);
            float zredCU = gate(pxU);
            if (Pr > 32) {                               // prefetch superchunk 1
                pxL = *(const uint4*)(gsrc + (size_t)s_rns[rsoff + min(32 + r16, Pr - 1)] * 128);
                pxU = *(const uint4*)(gsrc + (size_t)s_rns[rsoff + min(48 + r16, Pr - 1)] * 128);
            }
            bar_lds();                                   // publish Xh[0]

            floatx4 accmPL = {0, 0, 0, 0}, accmPU = {0, 0, 0, 0};
            float nsvPL[4] = {0, 0, 0, 0}, nsvPU[4] = {0, 0, 0, 0};
            int PcPL = 0, PcPU = 0, sbP = 0, c0P = 0;

            // F phase for superchunk at window-row base c0P (parity pb):
            // phase2 MFMA + nmbuf scatter + finalv atomics + COALESCED feats copy.
            auto phase2 = [&](int pb) {
                {
                    const _Float16* nrow = s_NSh[pb] + lm * NROW + (quad << 3);
#pragma unroll
                    for (int c = 0; c < 4; ++c)
                        accmPL = __builtin_amdgcn_mfma_f32_16x16x32_f16(
                            *(const half8*)(nrow + (c << 5)), wbm[c], accmPL, 0, 0, 0);
                }
                {
                    const _Float16* nrow = s_NSh[pb] + (16 + lm) * NROW + (quad << 3);
#pragma unroll
                    for (int c = 0; c < 4; ++c)
                        accmPU = __builtin_amdgcn_mfma_f32_16x16x32_f16(
                            *(const half8*)(nrow + (c << 5)), wbm[c], accmPU, 0, 0, 0);
                }
                float naL[4], naU[4];
                int nrL[4], nrU[4];
#pragma unroll
                for (int i = 0; i < 4; ++i) {
                    naL[i] = s_rna[pb][q4 + i];
                    naU[i] = s_rna[pb][16 + q4 + i];
                    nrL[i] = (int)s_rnode[c0P + q4 + i];
                    nrU[i] = (int)s_rnode[c0P + 16 + q4 + i];
                }
                if (PcPU == 16) {                        // fully-full superchunk
#pragma unroll
                    for (int i = 0; i < 4; ++i) {
                        nmbuf_h[(size_t)(sbP + q4 + i) * M + colw] =
                            (_Float16)(accmPL[i] + nmb_c);
                        nmbuf_h[(size_t)(sbP + 16 + q4 + i) * M + colw] =
                            (_Float16)(accmPU[i] + nmb_c);
                    }
#pragma unroll
                    for (int i = 0; i < 4; ++i) {
                        atomicAdd(finalv + (size_t)nrL[i] * H + colw, nsvPL[i] * naL[i]);
                        atomicAdd(finalv + (size_t)nrU[i] * H + colw, nsvPU[i] * naU[i]);
                    }
                } else {
#pragma unroll
                    for (int i = 0; i < 4; ++i) {
                        const int r = q4 + i;
                        if (r < PcPL) {
                            nmbuf_h[(size_t)(sbP + r) * M + colw] =
                                (_Float16)(accmPL[i] + nmb_c);
                            atomicAdd(finalv + (size_t)nrL[i] * H + colw,
                                      nsvPL[i] * naL[i]);
                        }
                        if (r < PcPU) {
                            nmbuf_h[(size_t)(sbP + 16 + r) * M + colw] =
                                (_Float16)(accmPU[i] + nmb_c);
                            atomicAdd(finalv + (size_t)nrU[i] * H + colw,
                                      nsvPU[i] * naU[i]);
                        }
                    }
                }
                // coalesced feats copy: one full fp16 row per 16 threads
                if (rowc < PcPL || (unsigned)(rowc - 16) < (unsigned)PcPU) {
                    const int nrr = (int)s_rnode[c0P + rowc];
                    const uint4 v = *(const uint4*)(s_NSh[pb] + rowc * NROW + (c16 << 3));
                    *(uint4*)(feats_h + (size_t)nrr * H + (c16 << 3)) = v;
                }
            };

            for (int c0 = 0; c0 < Pr; c0 += 32) {
                const int k = c0 >> 5;
                const int cur = k & 1, nxt = cur ^ 1;
                const int remn = Pr - c0;
                const int PcL = (remn >= 16) ? 16 : remn;
                const int PcU = (remn >= 32) ? 16 : (remn > 16 ? remn - 16 : 0);
                const bool hasnext = remn > 32;
                // stage superchunk k+1 from px regs; gate-reduce it
                float zredNL = 0.0f, zredNU = 0.0f;
                if (hasnext) {
                    *(uint4*)(s_Xh[nxt] + r16 * WROW + (c8 << 3)) = pxL;
                    *(uint4*)(s_Xh[nxt] + (16 + r16) * WROW + (c8 << 3)) = pxU;
                    zredNL = gate(pxL);
                    zredNU = gate(pxU);
                }
                // prefetch superchunk k+2
                if (remn > 64) {
                    pxL = *(const uint4*)(gsrc + (size_t)s_rns[rsoff + min(c0 + 64 + r16, Pr - 1)] * 128);
                    pxU = *(const uint4*)(gsrc + (size_t)s_rns[rsoff + min(c0 + 80 + r16, Pr - 1)] * 128);
                }
                // F: superchunk k-1 (NSh[nxt] holds parity (k-1)&1 == nxt)
                if (c0 > 0) phase2(nxt);
                // E: gate finalize superchunk k (1 thread per row; overlaps MFMA)
                if (sg == 0) {
                    if (r16 < PcL) {
                        const float z = zredCL + actb;
                        const float cnd = 1.0f / (1.0f + expf(-z));
                        const int nr = (int)s_rnode[c0 + r16];
                        const float ta = s_tact[nr];
                        const float na = (ta + cnd > 1.0f) ? (1.0f - ta) : cnd;
                        s_rna[cur][r16] = na;
                        s_tact[nr] = ta + na;
                    }
                    if (r16 < PcU) {
                        const float z = zredCU + actb;
                        const float cnd = 1.0f / (1.0f + expf(-z));
                        const int nr = (int)s_rnode[c0 + 16 + r16];
                        const float ta = s_tact[nr];
                        const float na = (ta + cnd > 1.0f) ? (1.0f - ta) : cnd;
                        s_rna[cur][16 + r16] = na;
                        s_tact[nr] = ta + na;
                    }
                }
                // D: phase1 MFMA superchunk k, L then U (guard-free; NSh only)
                floatx4 accmL, accmU;
                float nsvL[4], nsvU[4];
                {
                    floatx4 accn = {0, 0, 0, 0}, accm = {0, 0, 0, 0};
                    const _Float16* xrow = s_Xh[cur] + lm * WROW + (quad << 3);
                    half8 a[8];
#pragma unroll
                    for (int c = 0; c < 8; ++c) a[c] = *(const half8*)(xrow + (c << 5));
#pragma unroll
                    for (int c = 0; c < 8; ++c)
                        accn = __builtin_amdgcn_mfma_f32_16x16x32_f16(a[c], wbn[c], accn, 0, 0, 0);
#pragma unroll
                    for (int c = 4; c < 8; ++c)
                        accm = __builtin_amdgcn_mfma_f32_16x16x32_f16(a[c], wbm[c], accm, 0, 0, 0);
#pragma unroll
                    for (int i = 0; i < 4; ++i) {
                        nsvL[i] = fmaxf(accn[i] + nsb_c, 0.0f);
                        s_NSh[cur][(q4 + i) * NROW + colw] = (_Float16)nsvL[i];
                    }
                    accmL = accm;
                }
                {
                    floatx4 accn = {0, 0, 0, 0}, accm = {0, 0, 0, 0};
                    const _Float16* xrow = s_Xh[cur] + (16 + lm) * WROW + (quad << 3);
                    half8 a[8];
#pragma unroll
                    for (int c = 0; c < 8; ++c) a[c] = *(const half8*)(xrow + (c << 5));
#pragma unroll
                    for (int c = 0; c < 8; ++c)
                        accn = __builtin_amdgcn_mfma_f32_16x16x32_f16(a[c], wbn[c], accn, 0, 0, 0);
#pragma unroll
                    for (int c = 4; c < 8; ++c)
                        accm = __builtin_amdgcn_mfma_f32_16x16x32_f16(a[c], wbm[c], accm, 0, 0, 0);
#pragma unroll
                    for (int i = 0; i < 4; ++i) {
                        nsvU[i] = fmaxf(accn[i] + nsb_c, 0.0f);
                        s_NSh[cur][(16 + q4 + i) * NROW + colw] = (_Float16)nsvU[i];
                    }
                    accmU = accm;
                }
                // rotate pipeline state
                accmPL = accmL; accmPU = accmU;
#pragma unroll
                for (int i = 0; i < 4; ++i) { nsvPL[i] = nsvL[i]; nsvPU[i] = nsvU[i]; }
                PcPL = PcL; PcPU = PcU; sbP = gbase + base + c0; c0P = c0;
                zredCL = zredNL; zredCU = zredNU;
                bar_lds();               // publish Xh[nxt], NSh[cur], rna[cur]
            }
            // ---- epilogue: F for last superchunk (parity of c0P) ----
            phase2((c0P >> 5) & 1);
            base += Pr;
            // R7 barrier deleted: epilogue LDS reads are ordered before each
            // wave's R1 barrier; next round's s_rns writes happen after it.
        }

        // -------- enqueue (queue order via two-class prefix over flags) --------
        const bool pfa = (s_flag[t] & 1) != 0;
        const bool pfb = (s_flag[t] & 2) != 0;
        const unsigned long long mfa = __ballot(pfa);
        const unsigned long long mfb = __ballot(pfb);
        if (lane == 0) { s_wc[wid] = __popcll(mfa); s_wd[wid] = __popcll(mfb); }
        bar_lds();                                       // B3
        int TA = 0, TB = 0, preA = 0, preB = 0;
#pragma unroll
        for (int w = 0; w < 8; ++w) {
            TA += s_wc[w]; TB += s_wd[w];
            preA += (w < wid) ? s_wc[w] : 0;
            preB += (w < wid) ? s_wd[w] : 0;
        }
        const int T = TA + TB;
        if (T > 0) {
            const unsigned long long below = (1ull << lane) - 1ull;
            if (pfa) s_order[preA + __popcll(mfa & below)] = (short)t;
            if (pfb) s_order[TA + preB + __popcll(mfb & below)] = (short)(NT + t);
            bar_lds();                                   // B4
            for (int idx = t; idx < T * DEG; idx += NT) {
                const int e = (int)s_order[idx >> 4];
                const unsigned v = s_enq[e];
                const int nd = (int)(v & 0xffffu);
                const unsigned slot = v >> 16;
                const int q = tail + idx;
                if (q < QCAP)
                    s_q[q] = (unsigned)s_nb[nd * DEG + (idx & 15)] | (slot << 16);
            }
        }
        tail += DEG * T;
        gbase += T;
        head += W;
        bar_lds();                                       // B5 (LDS-only): s_q visible
    }

    // drain outstanding finalv atomics / stores before readout
    __syncthreads();

    // ---- readout (g/lg overlaid on dead mark region) ----
    if (t < H) {
        float g0 = 0, g1 = 0, g2 = 0, g3 = 0;
        for (int n = 0; n < NN; n += 4) {
            g0 += finalv[(n + 0) * H + t];
            g1 += finalv[(n + 1) * H + t];
            g2 += finalv[(n + 2) * H + t];
            g3 += finalv[(n + 3) * H + t];
        }
        s_g[t] = (g0 + g1) + (g2 + g3);
    }
    __syncthreads();
    if (t < PP * OUTF) {
        const int pp = t / OUTF, o = t % OUTF;
        float acc = dec_b[pp * OUTF + o];
        for (int h = 0; h < H; ++h) acc += s_g[h] * dec_w[(pp * H + h) * OUTF + o];
        s_lg[t] = acc;
    }
    __syncthreads();
    if (t < PP * OUTF) {
        const int pp = t / OUTF;
        float mx = -INFINITY;
        for (int o = 0; o < OUTF; ++o) mx = fmaxf(mx, s_lg[pp * OUTF + o]);
        float s = 0.0f;
        for (int o = 0; o < OUTF; ++o) s += expf(s_lg[pp * OUTF + o] - mx);
        out[t] = s_lg[t] - (mx + logf(s));
    }
}

extern "C" void kernel_launch(void* const* d_in, const int* in_sizes, int n_in,
                              void* d_out, int out_size, void* d_ws, size_t ws_size,
                              hipStream_t stream) {
    const float* xa        = (const float*)d_in[0];
    const float* fm        = (const float*)d_in[1];
    const int*   neighbors = (const int*)  d_in[2];
    const int*   nstart_p  = (const int*)  d_in[3];
    const float* enc_w     = (const float*)d_in[4];
    const float* enc_b     = (const float*)d_in[5];
    const float* ns_w      = (const float*)d_in[6];
    const float* ns_b      = (const float*)d_in[7];
    const float* nm_w      = (const float*)d_in[8];
    const float* nm_b      = (const float*)d_in[9];
    const float* act_w     = (const float*)d_in[10];
    const float* act_b     = (const float*)d_in[11];
    const float* dec_w     = (const float*)d_in[12];
    const float* dec_b     = (const float*)d_in[13];
    float* out = (float*)d_out;

    char* w = (char*)d_ws;
    _Float16* feats_h = (_Float16*)w;                 w += (size_t)NN * H * 2;
    float*    finalv  = (float*)w;                    w += (size_t)NN * H * 4;
    _Float16* nmbuf_h = (_Float16*)w;                 w += (size_t)NSLOT * M * 2;
    _Float16* wnsB    = (_Float16*)w;                 w += (size_t)128 * WROW * 2;
    _Float16* wnmB    = (_Float16*)w;                 w += (size_t)128 * WROW * 2;
    unsigned int* qpack = (unsigned int*)w;           // unused (LDS queue)

    init_kernel<<<NN, 128, 0, stream>>>(xa, fm, enc_w, enc_b, nstart_p,
                                        feats_h, finalv, nmbuf_h);
    pack_kernel<<<132, 256, 0, stream>>>(ns_w, nm_w, wnsB, wnmB);
    seq_kernel<<<1, NT, 0, stream>>>(neighbors, ns_b, nm_b,
                                     act_w, act_b, dec_w, dec_b, nstart_p,
                                     wnsB, wnmB,
                                     feats_h, finalv, nmbuf_h, qpack, out);
}

// Round 11
// 503.396 us; speedup vs baseline: 1.1009x; 1.0426x over previous
//
#include <hip/hip_runtime.h>
#include <math.h>

#define NN 1000
#define INF_ 32
#define H 128
#define M 128
#define DEG 16
#define PP 2
#define OUTF 10
#define MAXM (10 * NN)        // scan length; head <= MAXM
#define QCAP (MAXM + DEG)     // only entries < MAXM are ever read
#define NSLOT (MAXM + 128)    // nmbuf rows: nstart + total procs
#define NT 512
#define WQ (2 * NT)           // window size: 2 queue entries per thread
#define WROW 264              // padded halves per X/weight row (256+8)
#define NROW 136              // padded halves per NSh/NMh row (128+8)

typedef _Float16 half8 __attribute__((ext_vector_type(8)));
typedef float floatx4 __attribute__((ext_vector_type(4)));

// LDS-only barrier: publishes LDS writes without draining global (vmcnt) queue.
__device__ __forceinline__ void bar_lds() {
    asm volatile("s_waitcnt lgkmcnt(0)\n\ts_barrier" ::: "memory");
}

__global__ __launch_bounds__(128)
void init_kernel(const float* __restrict__ xa, const float* __restrict__ fm,
                 const float* __restrict__ enc_w, const float* __restrict__ enc_b,
                 const int* __restrict__ nstart_p,
                 _Float16* __restrict__ feats_h, float* __restrict__ finalv,
                 _Float16* __restrict__ nmbuf_h) {
    int b = blockIdx.x, t = threadIdx.x;
    float acc = enc_b[t];
    const float* xr = xa + b * INF_;
#pragma unroll
    for (int k = 0; k < INF_; ++k) acc += xr[k] * enc_w[k * H + t];
    feats_h[b * H + t] = (_Float16)acc;     // same rounding point as before
    finalv[b * H + t] = 0.0f;
    if (b < nstart_p[0]) nmbuf_h[(size_t)b * M + t] = (_Float16)fm[b * M + t];
}

// Pack weights fp16 transposed [n][k] with +8 pad: wB[n*WROW+k] = w[k][n].
__global__ __launch_bounds__(256)
void pack_kernel(const float* __restrict__ ns_w, const float* __restrict__ nm_w,
                 _Float16* __restrict__ wnsB, _Float16* __restrict__ wnmB) {
    const int idx = blockIdx.x * 256 + threadIdx.x;   // 128*WROW
    if (idx >= 128 * WROW) return;
    const int n = idx / WROW, k = idx % WROW;
    wnsB[idx] = (k < 256) ? (_Float16)ns_w[k * H + n] : (_Float16)0.0f;
    wnmB[idx] = (k < 256) ? (_Float16)nm_w[k * M + n] : (_Float16)0.0f;
}

// Rank-decomposed sequential ACT loop; MFMA matvecs with REGISTER-RESIDENT
// weight B-fragments; LDS-only fine barriers; LDS message queue.
// R10 (guard-free hot loop + coalesced nmbuf):
//  - only the LAST superchunk of a round can be partial -> in-loop F is
//    guard-free/full; partial logic lives only in the epilogue.
//  - nmbuf via LDS restage: F writes nm rows to s_NMh[2][] (bit-exact);
//    next iteration copies the published buffer to global as 1 uint4/thread
//    (2 full lines vs 8 partial-line scatters). Epilogue scatters directly.
//  - vmcnt drain moved pre-R3 (more overlap; same ordering guarantees).
__global__ __launch_bounds__(NT, 1)
void seq_kernel(const int* __restrict__ neighbors,
                const float* __restrict__ ns_b, const float* __restrict__ nm_b,
                const float* __restrict__ act_w, const float* __restrict__ act_b,
                const float* __restrict__ dec_w, const float* __restrict__ dec_b,
                const int* __restrict__ nstart_p,
                const _Float16* __restrict__ wnsB, const _Float16* __restrict__ wnmB,
                _Float16* __restrict__ feats_h, float* __restrict__ finalv,
                _Float16* __restrict__ nmbuf_h, unsigned int* __restrict__ qpack_unused,
                float* __restrict__ out) {
    __shared__ __align__(16) _Float16 s_Xh[2][32 * WROW];   // 33792 B
    __shared__ __align__(16) _Float16 s_NSh[2][32 * NROW];  // 17408 B
    __shared__ __align__(16) _Float16 s_NMh[2][32 * NROW];  // 17408 B
    __shared__ unsigned int s_q[QCAP];                      // 40064 B (LDS queue)
    __shared__ unsigned short s_nb[NN * DEG];               // 32000 B (neighbors u16)
    __shared__ float s_tact[NN];                            // 4000 B
    __shared__ int   s_mark[NN];                            // 4000 B (order/readout overlay)
    __shared__ float s_actw[H + M];
    __shared__ float s_nsb[H];
    __shared__ float s_nmb[M];
    __shared__ float s_rna[2][32];
    __shared__ unsigned short s_rns[2 * WQ];                // [0]=node, [WQ]=slot, rank order
    __shared__ unsigned int  s_enq[WQ];                     // node|newslot<<16 per entry
    __shared__ unsigned char s_flag[NT];                    // bit0: entry t, bit1: entry 512+t
    __shared__ int s_wc[8], s_wd[8];
    __shared__ int s_cnt;

    unsigned short* const s_rnode = s_rns;
    short* s_order = (short*)s_mark;                     // overlay: mark[0..511] = 1024 shorts
    float* s_g  = (float*)(s_mark + 512);                // overlay: readout only
    float* s_lg = (float*)(s_mark + 512 + 128);

    const int t = threadIdx.x;
    const int lane = t & 63, wid = t >> 6;
    const int quad = lane >> 4, lm = lane & 15;
    const int q4 = quad << 2;
    const int colw = (wid << 4) + lm;                    // this thread's output col
    const int sg = t & 31;                               // gate sub-lane
    const int r16 = t >> 5, c8 = t & 31;                 // staging coords (16x32)
    const int rowc = t >> 4, c16 = t & 15;               // row-copy coords (32x16)
    const int nstart = nstart_p[0];
    // loop-invariant staging source (feats row stride == nmbuf row stride == 128 halves)
    const int rsoff = (c8 < 16) ? 0 : WQ;
    const _Float16* const gsrc = (c8 < 16) ? (feats_h + c8 * 8)
                                           : (nmbuf_h + (c8 - 16) * 8);

    // ---- one-time: weight B-fragments into registers (loop-invariant) ----
    half8 wbn[8], wbm[8];
#pragma unroll
    for (int c = 0; c < 8; ++c) {
        wbn[c] = *(const half8*)(wnsB + (size_t)colw * WROW + (c << 5) + (quad << 3));
        wbm[c] = *(const half8*)(wnmB + (size_t)colw * WROW + (c << 5) + (quad << 3));
    }

    for (int i = t; i < NN; i += NT) { s_tact[i] = 0.0f; s_mark[i] = 0x7fffffff; }
    for (int i = t; i < nstart; i += NT) s_q[i] = (unsigned)i | ((unsigned)i << 16);
    for (int i = t; i < NN * DEG; i += NT) s_nb[i] = (unsigned short)neighbors[i];
    if (t < H + M) s_actw[t] = act_w[t];
    if (t < H) { s_nsb[t] = ns_b[t]; s_nmb[t] = nm_b[t]; }
    const float actb = act_b[0];
    __syncthreads();
    const float nsb_c = s_nsb[colw];
    const float nmb_c = s_nmb[colw];
    float aw[8];
#pragma unroll
    for (int j = 0; j < 8; ++j) aw[j] = s_actw[sg * 8 + j];

    // gate partial from staging registers (bitwise == old LDS-read path)
    auto gate = [&](uint4 v) -> float {
        const half8 hv = *(const half8*)&v;
        float p = 0.0f;
#pragma unroll
        for (int j = 0; j < 8; ++j) p += (float)hv[j] * aw[j];
#pragma unroll
        for (int off = 16; off > 0; off >>= 1) p += __shfl_down(p, off, 32);
        return p;                                        // valid in sg==0
    };

    int head = 0, tail = nstart, gbase = nstart;
    for (;;) {
        const int lim = min(tail, MAXM);
        if (head >= lim) break;
        const int W = min(WQ, lim - head);

        // ---- classify both entries; clear flags; repair order-overlaid mark ----
        int nodeA = 0, slotA = 0; bool remA = false;
        int nodeB = 0, slotB = 0; bool remB = false;
        if (t < W) {
            const unsigned v = s_q[head + t];
            nodeA = (int)(v & 0xffffu);
            slotA = (int)(v >> 16);
            remA = (s_tact[nodeA] <= 1.0f - 1e-7f);
        }
        if (NT + t < W) {
            const unsigned v = s_q[head + NT + t];
            nodeB = (int)(v & 0xffffu);
            slotB = (int)(v >> 16);
            remB = (s_tact[nodeB] <= 1.0f - 1e-7f);
        }
        s_flag[t] = 0;
        s_mark[t] = 0x7fffffff;                          // repair overlay (t<512 region)
        bar_lds();                                       // B1

        // ---------------- rank rounds ----------------
        int base = 0;
        for (;;) {
            const bool rem2a = remA && (s_tact[nodeA] <= 1.0f - 1e-7f);
            const bool rem2b = remB && (s_tact[nodeB] <= 1.0f - 1e-7f);
            if (rem2a) atomicMin(&s_mark[nodeA], t);
            if (rem2b) atomicMin(&s_mark[nodeB], NT + t);
            if (t == 0) s_cnt = 0;
            bar_lds();                                   // R1
            const bool winA = rem2a && (s_mark[nodeA] == t);
            const bool winB = rem2b && (s_mark[nodeB] == NT + t);
            const unsigned long long ma = __ballot(winA);
            const unsigned long long mb = __ballot(winB);
            const int ca = __popcll(ma), cb = __popcll(mb);
            int wbase = 0;
            if (lane == 0 && (ca + cb)) wbase = atomicAdd(&s_cnt, ca + cb);
            wbase = __shfl(wbase, 0, 64);
            const unsigned long long below = (1ull << lane) - 1ull;
            if (winA) {
                const int wrank = wbase + __popcll(ma & below);
                s_rns[wrank] = (unsigned short)nodeA;
                s_rns[WQ + wrank] = (unsigned short)slotA;
                s_enq[t] = (unsigned)nodeA | ((unsigned)(gbase + base + wrank) << 16);
                s_flag[t] |= 1;
            }
            if (winB) {
                const int wrank = wbase + ca + __popcll(mb & below);
                s_rns[wrank] = (unsigned short)nodeB;
                s_rns[WQ + wrank] = (unsigned short)slotB;
                s_enq[NT + t] = (unsigned)nodeB | ((unsigned)(gbase + base + wrank) << 16);
                s_flag[t] |= 2;
            }
            remA = rem2a && !winA;
            remB = rem2b && !winB;
            // drain prior stores here (overlapped by marking + ballot work);
            // the R3 barrier then publishes them before post-R3 staging loads.
            asm volatile("s_waitcnt vmcnt(0)" ::: "memory");
            bar_lds();                                   // R3: rnode/rslot/cnt ready
            if (rem2a) s_mark[nodeA] = 0x7fffffff;       // reset (barrier-separated)
            if (rem2b) s_mark[nodeB] = 0x7fffffff;
            const int Pr = s_cnt;
            if (Pr == 0) break;
            const int sb0 = gbase + base;

            // ============ single-barrier pipelined SUPERCHUNK loop (32 rows) ============
            // ---- prologue: superchunk 0 ----
            uint4 pxL = *(const uint4*)(gsrc + (size_t)s_rns[rsoff + min(r16, Pr - 1)] * 128);
            uint4 pxU = *(const uint4*)(gsrc + (size_t)s_rns[rsoff + min(16 + r16, Pr - 1)] * 128);
            *(uint4*)(s_Xh[0] + r16 * WROW + (c8 << 3)) = pxL;
            float zredCL = gate(pxL);
            float zredCU = 0.0f;
            if (Pr > 16) {
                *(uint4*)(s_Xh[0] + (16 + r16) * WROW + (c8 << 3)) = pxU;
                zredCU = gate(pxU);
            }
            if (Pr > 32) {                               // prefetch superchunk 1
                pxL = *(const uint4*)(gsrc + (size_t)s_rns[rsoff + min(32 + r16, Pr - 1)] * 128);
                pxU = *(const uint4*)(gsrc + (size_t)s_rns[rsoff + min(48 + r16, Pr - 1)] * 128);
            }
            bar_lds();                                   // publish Xh[0]

            floatx4 accmPL = {0, 0, 0, 0}, accmPU = {0, 0, 0, 0};
            float nsvPL[4] = {0, 0, 0, 0}, nsvPU[4] = {0, 0, 0, 0};

            for (int c0 = 0; c0 < Pr; c0 += 32) {
                const int k = c0 >> 5;
                const int cur = k & 1, nxt = cur ^ 1;
                const int remn = Pr - c0;
                const int PcL = (remn >= 16) ? 16 : remn;
                const int PcU = (remn >= 32) ? 16 : (remn > 16 ? remn - 16 : 0);
                // stage superchunk k+1 from px regs; gate-reduce it
                float zredNL = 0.0f, zredNU = 0.0f;
                if (remn > 32) {
                    *(uint4*)(s_Xh[nxt] + r16 * WROW + (c8 << 3)) = pxL;
                    zredNL = gate(pxL);
                    if (remn > 48) {
                        *(uint4*)(s_Xh[nxt] + (16 + r16) * WROW + (c8 << 3)) = pxU;
                        zredNU = gate(pxU);
                    }
                }
                // prefetch superchunk k+2
                if (remn > 64) {
                    pxL = *(const uint4*)(gsrc + (size_t)s_rns[rsoff + min(c0 + 64 + r16, Pr - 1)] * 128);
                    pxU = *(const uint4*)(gsrc + (size_t)s_rns[rsoff + min(c0 + 80 + r16, Pr - 1)] * 128);
                }
                // COPY: superchunk k-2's nm rows (full) LDS -> global, coalesced
                if (c0 >= 64) {
                    const int sbC = sb0 + c0 - 64;
                    const uint4 v = *(const uint4*)(s_NMh[cur] + rowc * NROW + (c16 << 3));
                    *(uint4*)(nmbuf_h + (size_t)(sbC + rowc) * M + (c16 << 3)) = v;
                }
                // F: superchunk k-1 (FULL; guard-free): phase2 MFMA + nm->LDS +
                // finalv atomics + coalesced feats copy.
                if (c0 > 0) {
                    const int c0F = c0 - 32;
                    {
                        const _Float16* nrow = s_NSh[nxt] + lm * NROW + (quad << 3);
#pragma unroll
                        for (int c = 0; c < 4; ++c)
                            accmPL = __builtin_amdgcn_mfma_f32_16x16x32_f16(
                                *(const half8*)(nrow + (c << 5)), wbm[c], accmPL, 0, 0, 0);
                    }
                    {
                        const _Float16* nrow = s_NSh[nxt] + (16 + lm) * NROW + (quad << 3);
#pragma unroll
                        for (int c = 0; c < 4; ++c)
                            accmPU = __builtin_amdgcn_mfma_f32_16x16x32_f16(
                                *(const half8*)(nrow + (c << 5)), wbm[c], accmPU, 0, 0, 0);
                    }
#pragma unroll
                    for (int i = 0; i < 4; ++i) {
                        s_NMh[nxt][(q4 + i) * NROW + colw] = (_Float16)(accmPL[i] + nmb_c);
                        s_NMh[nxt][(16 + q4 + i) * NROW + colw] = (_Float16)(accmPU[i] + nmb_c);
                    }
#pragma unroll
                    for (int i = 0; i < 4; ++i) {
                        const float naL = s_rna[nxt][q4 + i];
                        const float naU = s_rna[nxt][16 + q4 + i];
                        const int nrL = (int)s_rnode[c0F + q4 + i];
                        const int nrU = (int)s_rnode[c0F + 16 + q4 + i];
                        atomicAdd(finalv + (size_t)nrL * H + colw, nsvPL[i] * naL);
                        atomicAdd(finalv + (size_t)nrU * H + colw, nsvPU[i] * naU);
                    }
                    {   // coalesced feats copy (full)
                        const int nrr = (int)s_rnode[c0F + rowc];
                        const uint4 v = *(const uint4*)(s_NSh[nxt] + rowc * NROW + (c16 << 3));
                        *(uint4*)(feats_h + (size_t)nrr * H + (c16 << 3)) = v;
                    }
                }
                // E: gate finalize superchunk k (1 thread per row; overlaps MFMA)
                if (sg == 0) {
                    if (r16 < PcL) {
                        const float z = zredCL + actb;
                        const float cnd = 1.0f / (1.0f + expf(-z));
                        const int nr = (int)s_rnode[c0 + r16];
                        const float ta = s_tact[nr];
                        const float na = (ta + cnd > 1.0f) ? (1.0f - ta) : cnd;
                        s_rna[cur][r16] = na;
                        s_tact[nr] = ta + na;
                    }
                    if (r16 < PcU) {
                        const float z = zredCU + actb;
                        const float cnd = 1.0f / (1.0f + expf(-z));
                        const int nr = (int)s_rnode[c0 + 16 + r16];
                        const float ta = s_tact[nr];
                        const float na = (ta + cnd > 1.0f) ? (1.0f - ta) : cnd;
                        s_rna[cur][16 + r16] = na;
                        s_tact[nr] = ta + na;
                    }
                }
                // D: phase1 MFMA superchunk k, L always; U only if tile-half live
                floatx4 accmL = {0, 0, 0, 0}, accmU = {0, 0, 0, 0};
                float nsvL[4] = {0, 0, 0, 0}, nsvU[4] = {0, 0, 0, 0};
                {
                    floatx4 accn = {0, 0, 0, 0}, accm = {0, 0, 0, 0};
                    const _Float16* xrow = s_Xh[cur] + lm * WROW + (quad << 3);
                    half8 a[8];
#pragma unroll
                    for (int c = 0; c < 8; ++c) a[c] = *(const half8*)(xrow + (c << 5));
#pragma unroll
                    for (int c = 0; c < 8; ++c)
                        accn = __builtin_amdgcn_mfma_f32_16x16x32_f16(a[c], wbn[c], accn, 0, 0, 0);
#pragma unroll
                    for (int c = 4; c < 8; ++c)
                        accm = __builtin_amdgcn_mfma_f32_16x16x32_f16(a[c], wbm[c], accm, 0, 0, 0);
#pragma unroll
                    for (int i = 0; i < 4; ++i) {
                        nsvL[i] = fmaxf(accn[i] + nsb_c, 0.0f);
                        s_NSh[cur][(q4 + i) * NROW + colw] = (_Float16)nsvL[i];
                    }
                    accmL = accm;
                }
                if (PcU > 0) {
                    floatx4 accn = {0, 0, 0, 0}, accm = {0, 0, 0, 0};
                    const _Float16* xrow = s_Xh[cur] + (16 + lm) * WROW + (quad << 3);
                    half8 a[8];
#pragma unroll
                    for (int c = 0; c < 8; ++c) a[c] = *(const half8*)(xrow + (c << 5));
#pragma unroll
                    for (int c = 0; c < 8; ++c)
                        accn = __builtin_amdgcn_mfma_f32_16x16x32_f16(a[c], wbn[c], accn, 0, 0, 0);
#pragma unroll
                    for (int c = 4; c < 8; ++c)
                        accm = __builtin_amdgcn_mfma_f32_16x16x32_f16(a[c], wbm[c], accm, 0, 0, 0);
#pragma unroll
                    for (int i = 0; i < 4; ++i) {
                        nsvU[i] = fmaxf(accn[i] + nsb_c, 0.0f);
                        s_NSh[cur][(16 + q4 + i) * NROW + colw] = (_Float16)nsvU[i];
                    }
                    accmU = accm;
                }
                // rotate pipeline state
                accmPL = accmL; accmPU = accmU;
#pragma unroll
                for (int i = 0; i < 4; ++i) { nsvPL[i] = nsvL[i]; nsvPU[i] = nsvU[i]; }
                zredCL = zredNL; zredCU = zredNU;
                bar_lds();               // publish Xh[nxt], NSh[cur], NMh[nxt], rna[cur]
            }
            // ---- epilogue ----
            {
                const int c0L = ((Pr - 1) >> 5) << 5;    // last superchunk base
                const int pbL = (c0L >> 5) & 1;
                const int lastn = Pr - c0L;
                const int PcLL = (lastn >= 16) ? 16 : lastn;
                const int PcLU = (lastn > 16) ? lastn - 16 : 0;
                if (Pr > 32) {                           // copy superchunk K-2 (full)
                    const int sbC = sb0 + c0L - 32;
                    const uint4 v = *(const uint4*)(s_NMh[pbL ^ 1] + rowc * NROW + (c16 << 3));
                    *(uint4*)(nmbuf_h + (size_t)(sbC + rowc) * M + (c16 << 3)) = v;
                }
                // phase2 DIRECT for last superchunk (partial-capable)
                {
                    const _Float16* nrow = s_NSh[pbL] + lm * NROW + (quad << 3);
#pragma unroll
                    for (int c = 0; c < 4; ++c)
                        accmPL = __builtin_amdgcn_mfma_f32_16x16x32_f16(
                            *(const half8*)(nrow + (c << 5)), wbm[c], accmPL, 0, 0, 0);
                }
                if (PcLU > 0) {
                    const _Float16* nrow = s_NSh[pbL] + (16 + lm) * NROW + (quad << 3);
#pragma unroll
                    for (int c = 0; c < 4; ++c)
                        accmPU = __builtin_amdgcn_mfma_f32_16x16x32_f16(
                            *(const half8*)(nrow + (c << 5)), wbm[c], accmPU, 0, 0, 0);
                }
                const int sbL = sb0 + c0L;
#pragma unroll
                for (int i = 0; i < 4; ++i) {
                    const int r = q4 + i;
                    if (r < PcLL) {
                        nmbuf_h[(size_t)(sbL + r) * M + colw] =
                            (_Float16)(accmPL[i] + nmb_c);
                        atomicAdd(finalv + (size_t)s_rnode[c0L + r] * H + colw,
                                  nsvPL[i] * s_rna[pbL][r]);
                    }
                    if (r < PcLU) {
                        nmbuf_h[(size_t)(sbL + 16 + r) * M + colw] =
                            (_Float16)(accmPU[i] + nmb_c);
                        atomicAdd(finalv + (size_t)s_rnode[c0L + 16 + r] * H + colw,
                                  nsvPU[i] * s_rna[pbL][16 + r]);
                    }
                }
                // coalesced feats copy (guarded)
                if (rowc < PcLL || (unsigned)(rowc - 16) < (unsigned)PcLU) {
                    const int nrr = (int)s_rnode[c0L + rowc];
                    const uint4 v = *(const uint4*)(s_NSh[pbL] + rowc * NROW + (c16 << 3));
                    *(uint4*)(feats_h + (size_t)nrr * H + (c16 << 3)) = v;
                }
            }
            base += Pr;
        }

        // -------- enqueue (queue order via two-class prefix over flags) --------
        const bool pfa = (s_flag[t] & 1) != 0;
        const bool pfb = (s_flag[t] & 2) != 0;
        const unsigned long long mfa = __ballot(pfa);
        const unsigned long long mfb = __ballot(pfb);
        if (lane == 0) { s_wc[wid] = __popcll(mfa); s_wd[wid] = __popcll(mfb); }
        bar_lds();                                       // B3
        int TA = 0, TB = 0, preA = 0, preB = 0;
#pragma unroll
        for (int w = 0; w < 8; ++w) {
            TA += s_wc[w]; TB += s_wd[w];
            preA += (w < wid) ? s_wc[w] : 0;
            preB += (w < wid) ? s_wd[w] : 0;
        }
        const int T = TA + TB;
        if (T > 0) {
            const unsigned long long below = (1ull << lane) - 1ull;
            if (pfa) s_order[preA + __popcll(mfa & below)] = (short)t;
            if (pfb) s_order[TA + preB + __popcll(mfb & below)] = (short)(NT + t);
            bar_lds();                                   // B4
            for (int idx = t; idx < T * DEG; idx += NT) {
                const int e = (int)s_order[idx >> 4];
                const unsigned v = s_enq[e];
                const int nd = (int)(v & 0xffffu);
                const unsigned slot = v >> 16;
                const int q = tail + idx;
                if (q < QCAP)
                    s_q[q] = (unsigned)s_nb[nd * DEG + (idx & 15)] | (slot << 16);
            }
        }
        tail += DEG * T;
        gbase += T;
        head += W;
        bar_lds();                                       // B5 (LDS-only): s_q visible
    }

    // drain outstanding finalv atomics / stores before readout
    __syncthreads();

    // ---- readout (g/lg overlaid on dead mark region) ----
    if (t < H) {
        float g0 = 0, g1 = 0, g2 = 0, g3 = 0;
        for (int n = 0; n < NN; n += 4) {
            g0 += finalv[(n + 0) * H + t];
            g1 += finalv[(n + 1) * H + t];
            g2 += finalv[(n + 2) * H + t];
            g3 += finalv[(n + 3) * H + t];
        }
        s_g[t] = (g0 + g1) + (g2 + g3);
    }
    __syncthreads();
    if (t < PP * OUTF) {
        const int pp = t / OUTF, o = t % OUTF;
        float acc = dec_b[pp * OUTF + o];
        for (int h = 0; h < H; ++h) acc += s_g[h] * dec_w[(pp * H + h) * OUTF + o];
        s_lg[t] = acc;
    }
    __syncthreads();
    if (t < PP * OUTF) {
        const int pp = t / OUTF;
        float mx = -INFINITY;
        for (int o = 0; o < OUTF; ++o) mx = fmaxf(mx, s_lg[pp * OUTF + o]);
        float s = 0.0f;
        for (int o = 0; o < OUTF; ++o) s += expf(s_lg[pp * OUTF + o] - mx);
        out[t] = s_lg[t] - (mx + logf(s));
    }
}

extern "C" void kernel_launch(void* const* d_in, const int* in_sizes, int n_in,
                              void* d_out, int out_size, void* d_ws, size_t ws_size,
                              hipStream_t stream) {
    const float* xa        = (const float*)d_in[0];
    const float* fm        = (const float*)d_in[1];
    const int*   neighbors = (const int*)  d_in[2];
    const int*   nstart_p  = (const int*)  d_in[3];
    const float* enc_w     = (const float*)d_in[4];
    const float* enc_b     = (const float*)d_in[5];
    const float* ns_w      = (const float*)d_in[6];
    const float* ns_b      = (const float*)d_in[7];
    const float* nm_w      = (const float*)d_in[8];
    const float* nm_b      = (const float*)d_in[9];
    const float* act_w     = (const float*)d_in[10];
    const float* act_b     = (const float*)d_in[11];
    const float* dec_w     = (const float*)d_in[12];
    const float* dec_b     = (const float*)d_in[13];
    float* out = (float*)d_out;

    char* w = (char*)d_ws;
    _Float16* feats_h = (_Float16*)w;                 w += (size_t)NN * H * 2;
    float*    finalv  = (float*)w;                    w += (size_t)NN * H * 4;
    _Float16* nmbuf_h = (_Float16*)w;                 w += (size_t)NSLOT * M * 2;
    _Float16* wnsB    = (_Float16*)w;                 w += (size_t)128 * WROW * 2;
    _Float16* wnmB    = (_Float16*)w;                 w += (size_t)128 * WROW * 2;
    unsigned int* qpack = (unsigned int*)w;           // unused (LDS queue)

    init_kernel<<<NN, 128, 0, stream>>>(xa, fm, enc_w, enc_b, nstart_p,
                                        feats_h, finalv, nmbuf_h);
    pack_kernel<<<132, 256, 0, stream>>>(ns_w, nm_w, wnsB, wnmB);
    seq_kernel<<<1, NT, 0, stream>>>(neighbors, ns_b, nm_b,
                                     act_w, act_b, dec_w, dec_b, nstart_p,
                                     wnsB, wnmB,
                                     feats_h, finalv, nmbuf_h, qpack, out);
}

// Round 12
// 500.340 us; speedup vs baseline: 1.1076x; 1.0061x over previous
//
#include <hip/hip_runtime.h>
#include <math.h>

#define NN 1000
#define INF_ 32
#define H 128
#define M 128
#define DEG 16
#define PP 2
#define OUTF 10
#define MAXM (10 * NN)        // scan length; head <= MAXM
#define QCAP (MAXM + DEG)     // only entries < MAXM are ever read
#define NSLOT (MAXM + 128)    // nmbuf rows: nstart + total procs
#define NT 512
#define WQ (2 * NT)           // window size: 2 queue entries per thread
#define WROW 264              // padded halves per X/weight row (256+8)
#define NROW 136              // padded halves per NSh/NMh row (128+8)

typedef _Float16 half8 __attribute__((ext_vector_type(8)));
typedef float floatx4 __attribute__((ext_vector_type(4)));

// LDS-only barrier: publishes LDS writes without draining global (vmcnt) queue.
__device__ __forceinline__ void bar_lds() {
    asm volatile("s_waitcnt lgkmcnt(0)\n\ts_barrier" ::: "memory");
}

__global__ __launch_bounds__(128)
void init_kernel(const float* __restrict__ xa, const float* __restrict__ fm,
                 const float* __restrict__ enc_w, const float* __restrict__ enc_b,
                 const int* __restrict__ nstart_p,
                 _Float16* __restrict__ feats_h, float* __restrict__ finalv,
                 _Float16* __restrict__ nmbuf_h) {
    int b = blockIdx.x, t = threadIdx.x;
    float acc = enc_b[t];
    const float* xr = xa + b * INF_;
#pragma unroll
    for (int k = 0; k < INF_; ++k) acc += xr[k] * enc_w[k * H + t];
    feats_h[b * H + t] = (_Float16)acc;     // same rounding point as before
    finalv[b * H + t] = 0.0f;
    if (b < nstart_p[0]) nmbuf_h[(size_t)b * M + t] = (_Float16)fm[b * M + t];
}

// Pack weights fp16 transposed [n][k] with +8 pad: wB[n*WROW+k] = w[k][n].
__global__ __launch_bounds__(256)
void pack_kernel(const float* __restrict__ ns_w, const float* __restrict__ nm_w,
                 _Float16* __restrict__ wnsB, _Float16* __restrict__ wnmB) {
    const int idx = blockIdx.x * 256 + threadIdx.x;   // 128*WROW
    if (idx >= 128 * WROW) return;
    const int n = idx / WROW, k = idx % WROW;
    wnsB[idx] = (k < 256) ? (_Float16)ns_w[k * H + n] : (_Float16)0.0f;
    wnmB[idx] = (k < 256) ? (_Float16)nm_w[k * M + n] : (_Float16)0.0f;
}

// Rank-decomposed sequential ACT loop; MFMA matvecs with REGISTER-RESIDENT
// weight B-fragments; LDS-only fine barriers; LDS message queue.
// R11 (fused round transitions on R10):
//  - next round's MARKING (atomicMin + s_cnt reset) moved into the same
//    barrier interval as the epilogue F: both depend only on state published
//    by the final chunk-loop barrier and touch disjoint memory. The final
//    loop barrier doubles as R1. Epilogue stores get the ballot interval to
//    retire before the pre-R3 vmcnt drain.
__global__ __launch_bounds__(NT, 1)
void seq_kernel(const int* __restrict__ neighbors,
                const float* __restrict__ ns_b, const float* __restrict__ nm_b,
                const float* __restrict__ act_w, const float* __restrict__ act_b,
                const float* __restrict__ dec_w, const float* __restrict__ dec_b,
                const int* __restrict__ nstart_p,
                const _Float16* __restrict__ wnsB, const _Float16* __restrict__ wnmB,
                _Float16* __restrict__ feats_h, float* __restrict__ finalv,
                _Float16* __restrict__ nmbuf_h, unsigned int* __restrict__ qpack_unused,
                float* __restrict__ out) {
    __shared__ __align__(16) _Float16 s_Xh[2][32 * WROW];   // 33792 B
    __shared__ __align__(16) _Float16 s_NSh[2][32 * NROW];  // 17408 B
    __shared__ __align__(16) _Float16 s_NMh[2][32 * NROW];  // 17408 B
    __shared__ unsigned int s_q[QCAP];                      // 40064 B (LDS queue)
    __shared__ unsigned short s_nb[NN * DEG];               // 32000 B (neighbors u16)
    __shared__ float s_tact[NN];                            // 4000 B
    __shared__ int   s_mark[NN];                            // 4000 B (order/readout overlay)
    __shared__ float s_actw[H + M];
    __shared__ float s_nsb[H];
    __shared__ float s_nmb[M];
    __shared__ float s_rna[2][32];
    __shared__ unsigned short s_rns[2 * WQ];                // [0]=node, [WQ]=slot, rank order
    __shared__ unsigned int  s_enq[WQ];                     // node|newslot<<16 per entry
    __shared__ unsigned char s_flag[NT];                    // bit0: entry t, bit1: entry 512+t
    __shared__ int s_wc[8], s_wd[8];
    __shared__ int s_cnt;

    unsigned short* const s_rnode = s_rns;
    short* s_order = (short*)s_mark;                     // overlay: mark[0..511] = 1024 shorts
    float* s_g  = (float*)(s_mark + 512);                // overlay: readout only
    float* s_lg = (float*)(s_mark + 512 + 128);

    const int t = threadIdx.x;
    const int lane = t & 63, wid = t >> 6;
    const int quad = lane >> 4, lm = lane & 15;
    const int q4 = quad << 2;
    const int colw = (wid << 4) + lm;                    // this thread's output col
    const int sg = t & 31;                               // gate sub-lane
    const int r16 = t >> 5, c8 = t & 31;                 // staging coords (16x32)
    const int rowc = t >> 4, c16 = t & 15;               // row-copy coords (32x16)
    const int nstart = nstart_p[0];
    // loop-invariant staging source (feats row stride == nmbuf row stride == 128 halves)
    const int rsoff = (c8 < 16) ? 0 : WQ;
    const _Float16* const gsrc = (c8 < 16) ? (feats_h + c8 * 8)
                                           : (nmbuf_h + (c8 - 16) * 8);

    // ---- one-time: weight B-fragments into registers (loop-invariant) ----
    half8 wbn[8], wbm[8];
#pragma unroll
    for (int c = 0; c < 8; ++c) {
        wbn[c] = *(const half8*)(wnsB + (size_t)colw * WROW + (c << 5) + (quad << 3));
        wbm[c] = *(const half8*)(wnmB + (size_t)colw * WROW + (c << 5) + (quad << 3));
    }

    for (int i = t; i < NN; i += NT) { s_tact[i] = 0.0f; s_mark[i] = 0x7fffffff; }
    for (int i = t; i < nstart; i += NT) s_q[i] = (unsigned)i | ((unsigned)i << 16);
    for (int i = t; i < NN * DEG; i += NT) s_nb[i] = (unsigned short)neighbors[i];
    if (t < H + M) s_actw[t] = act_w[t];
    if (t < H) { s_nsb[t] = ns_b[t]; s_nmb[t] = nm_b[t]; }
    const float actb = act_b[0];
    __syncthreads();
    const float nsb_c = s_nsb[colw];
    const float nmb_c = s_nmb[colw];
    float aw[8];
#pragma unroll
    for (int j = 0; j < 8; ++j) aw[j] = s_actw[sg * 8 + j];

    // gate partial from staging registers (bitwise == old LDS-read path)
    auto gate = [&](uint4 v) -> float {
        const half8 hv = *(const half8*)&v;
        float p = 0.0f;
#pragma unroll
        for (int j = 0; j < 8; ++j) p += (float)hv[j] * aw[j];
#pragma unroll
        for (int off = 16; off > 0; off >>= 1) p += __shfl_down(p, off, 32);
        return p;                                        // valid in sg==0
    };

    int head = 0, tail = nstart, gbase = nstart;
    for (;;) {
        const int lim = min(tail, MAXM);
        if (head >= lim) break;
        const int W = min(WQ, lim - head);

        // ---- classify both entries; clear flags; repair order-overlaid mark ----
        int nodeA = 0, slotA = 0; bool remA = false;
        int nodeB = 0, slotB = 0; bool remB = false;
        if (t < W) {
            const unsigned v = s_q[head + t];
            nodeA = (int)(v & 0xffffu);
            slotA = (int)(v >> 16);
            remA = (s_tact[nodeA] <= 1.0f - 1e-7f);
        }
        if (NT + t < W) {
            const unsigned v = s_q[head + NT + t];
            nodeB = (int)(v & 0xffffu);
            slotB = (int)(v >> 16);
            remB = (s_tact[nodeB] <= 1.0f - 1e-7f);
        }
        s_flag[t] = 0;
        s_mark[t] = 0x7fffffff;                          // repair overlay (t<512 region)
        bar_lds();                                       // B1

        // ---------------- rank rounds (fused transitions) ----------------
        int base = 0;
        // initial marking interval (round 1)
        bool rem2a = remA && (s_tact[nodeA] <= 1.0f - 1e-7f);
        bool rem2b = remB && (s_tact[nodeB] <= 1.0f - 1e-7f);
        if (rem2a) atomicMin(&s_mark[nodeA], t);
        if (rem2b) atomicMin(&s_mark[nodeB], NT + t);
        if (t == 0) s_cnt = 0;
        for (;;) {
            bar_lds();                                   // R1 (or final chunk bar)
            const bool winA = rem2a && (s_mark[nodeA] == t);
            const bool winB = rem2b && (s_mark[nodeB] == NT + t);
            const unsigned long long ma = __ballot(winA);
            const unsigned long long mb = __ballot(winB);
            const int ca = __popcll(ma), cb = __popcll(mb);
            int wbase = 0;
            if (lane == 0 && (ca + cb)) wbase = atomicAdd(&s_cnt, ca + cb);
            wbase = __shfl(wbase, 0, 64);
            const unsigned long long below = (1ull << lane) - 1ull;
            if (winA) {
                const int wrank = wbase + __popcll(ma & below);
                s_rns[wrank] = (unsigned short)nodeA;
                s_rns[WQ + wrank] = (unsigned short)slotA;
                s_enq[t] = (unsigned)nodeA | ((unsigned)(gbase + base + wrank) << 16);
                s_flag[t] |= 1;
            }
            if (winB) {
                const int wrank = wbase + ca + __popcll(mb & below);
                s_rns[wrank] = (unsigned short)nodeB;
                s_rns[WQ + wrank] = (unsigned short)slotB;
                s_enq[NT + t] = (unsigned)nodeB | ((unsigned)(gbase + base + wrank) << 16);
                s_flag[t] |= 2;
            }
            remA = rem2a && !winA;
            remB = rem2b && !winB;
            // drain prior stores (epilogue stores issued one interval ago);
            // the R3 barrier then publishes them before post-R3 staging loads.
            asm volatile("s_waitcnt vmcnt(0)" ::: "memory");
            bar_lds();                                   // R3: rnode/rslot/cnt ready
            if (rem2a) s_mark[nodeA] = 0x7fffffff;       // reset (barrier-separated)
            if (rem2b) s_mark[nodeB] = 0x7fffffff;
            const int Pr = s_cnt;
            if (Pr == 0) break;
            const int sb0 = gbase + base;
            base += Pr;

            // ============ single-barrier pipelined SUPERCHUNK loop (32 rows) ============
            // ---- prologue: superchunk 0 ----
            uint4 pxL = *(const uint4*)(gsrc + (size_t)s_rns[rsoff + min(r16, Pr - 1)] * 128);
            uint4 pxU = *(const uint4*)(gsrc + (size_t)s_rns[rsoff + min(16 + r16, Pr - 1)] * 128);
            *(uint4*)(s_Xh[0] + r16 * WROW + (c8 << 3)) = pxL;
            float zredCL = gate(pxL);
            float zredCU = 0.0f;
            if (Pr > 16) {
                *(uint4*)(s_Xh[0] + (16 + r16) * WROW + (c8 << 3)) = pxU;
                zredCU = gate(pxU);
            }
            if (Pr > 32) {                               // prefetch superchunk 1
                pxL = *(const uint4*)(gsrc + (size_t)s_rns[rsoff + min(32 + r16, Pr - 1)] * 128);
                pxU = *(const uint4*)(gsrc + (size_t)s_rns[rsoff + min(48 + r16, Pr - 1)] * 128);
            }
            bar_lds();                                   // publish Xh[0]

            floatx4 accmPL = {0, 0, 0, 0}, accmPU = {0, 0, 0, 0};
            float nsvPL[4] = {0, 0, 0, 0}, nsvPU[4] = {0, 0, 0, 0};

            for (int c0 = 0; c0 < Pr; c0 += 32) {
                const int k = c0 >> 5;
                const int cur = k & 1, nxt = cur ^ 1;
                const int remn = Pr - c0;
                const int PcL = (remn >= 16) ? 16 : remn;
                const int PcU = (remn >= 32) ? 16 : (remn > 16 ? remn - 16 : 0);
                // stage superchunk k+1 from px regs; gate-reduce it
                float zredNL = 0.0f, zredNU = 0.0f;
                if (remn > 32) {
                    *(uint4*)(s_Xh[nxt] + r16 * WROW + (c8 << 3)) = pxL;
                    zredNL = gate(pxL);
                    if (remn > 48) {
                        *(uint4*)(s_Xh[nxt] + (16 + r16) * WROW + (c8 << 3)) = pxU;
                        zredNU = gate(pxU);
                    }
                }
                // prefetch superchunk k+2
                if (remn > 64) {
                    pxL = *(const uint4*)(gsrc + (size_t)s_rns[rsoff + min(c0 + 64 + r16, Pr - 1)] * 128);
                    pxU = *(const uint4*)(gsrc + (size_t)s_rns[rsoff + min(c0 + 80 + r16, Pr - 1)] * 128);
                }
                // COPY: superchunk k-2's nm rows (full) LDS -> global, coalesced
                if (c0 >= 64) {
                    const int sbC = sb0 + c0 - 64;
                    const uint4 v = *(const uint4*)(s_NMh[cur] + rowc * NROW + (c16 << 3));
                    *(uint4*)(nmbuf_h + (size_t)(sbC + rowc) * M + (c16 << 3)) = v;
                }
                // F: superchunk k-1 (FULL; guard-free): phase2 MFMA + nm->LDS +
                // finalv atomics + coalesced feats copy.
                if (c0 > 0) {
                    const int c0F = c0 - 32;
                    {
                        const _Float16* nrow = s_NSh[nxt] + lm * NROW + (quad << 3);
#pragma unroll
                        for (int c = 0; c < 4; ++c)
                            accmPL = __builtin_amdgcn_mfma_f32_16x16x32_f16(
                                *(const half8*)(nrow + (c << 5)), wbm[c], accmPL, 0, 0, 0);
                    }
                    {
                        const _Float16* nrow = s_NSh[nxt] + (16 + lm) * NROW + (quad << 3);
#pragma unroll
                        for (int c = 0; c < 4; ++c)
                            accmPU = __builtin_amdgcn_mfma_f32_16x16x32_f16(
                                *(const half8*)(nrow + (c << 5)), wbm[c], accmPU, 0, 0, 0);
                    }
#pragma unroll
                    for (int i = 0; i < 4; ++i) {
                        s_NMh[nxt][(q4 + i) * NROW + colw] = (_Float16)(accmPL[i] + nmb_c);
                        s_NMh[nxt][(16 + q4 + i) * NROW + colw] = (_Float16)(accmPU[i] + nmb_c);
                    }
#pragma unroll
                    for (int i = 0; i < 4; ++i) {
                        const float naL = s_rna[nxt][q4 + i];
                        const float naU = s_rna[nxt][16 + q4 + i];
                        const int nrL = (int)s_rnode[c0F + q4 + i];
                        const int nrU = (int)s_rnode[c0F + 16 + q4 + i];
                        atomicAdd(finalv + (size_t)nrL * H + colw, nsvPL[i] * naL);
                        atomicAdd(finalv + (size_t)nrU * H + colw, nsvPU[i] * naU);
                    }
                    {   // coalesced feats copy (full)
                        const int nrr = (int)s_rnode[c0F + rowc];
                        const uint4 v = *(const uint4*)(s_NSh[nxt] + rowc * NROW + (c16 << 3));
                        *(uint4*)(feats_h + (size_t)nrr * H + (c16 << 3)) = v;
                    }
                }
                // E: gate finalize superchunk k (1 thread per row; overlaps MFMA)
                if (sg == 0) {
                    if (r16 < PcL) {
                        const float z = zredCL + actb;
                        const float cnd = 1.0f / (1.0f + expf(-z));
                        const int nr = (int)s_rnode[c0 + r16];
                        const float ta = s_tact[nr];
                        const float na = (ta + cnd > 1.0f) ? (1.0f - ta) : cnd;
                        s_rna[cur][r16] = na;
                        s_tact[nr] = ta + na;
                    }
                    if (r16 < PcU) {
                        const float z = zredCU + actb;
                        const float cnd = 1.0f / (1.0f + expf(-z));
                        const int nr = (int)s_rnode[c0 + 16 + r16];
                        const float ta = s_tact[nr];
                        const float na = (ta + cnd > 1.0f) ? (1.0f - ta) : cnd;
                        s_rna[cur][16 + r16] = na;
                        s_tact[nr] = ta + na;
                    }
                }
                // D: phase1 MFMA superchunk k, L always; U only if tile-half live
                floatx4 accmL = {0, 0, 0, 0}, accmU = {0, 0, 0, 0};
                float nsvL[4] = {0, 0, 0, 0}, nsvU[4] = {0, 0, 0, 0};
                {
                    floatx4 accn = {0, 0, 0, 0}, accm = {0, 0, 0, 0};
                    const _Float16* xrow = s_Xh[cur] + lm * WROW + (quad << 3);
                    half8 a[8];
#pragma unroll
                    for (int c = 0; c < 8; ++c) a[c] = *(const half8*)(xrow + (c << 5));
#pragma unroll
                    for (int c = 0; c < 8; ++c)
                        accn = __builtin_amdgcn_mfma_f32_16x16x32_f16(a[c], wbn[c], accn, 0, 0, 0);
#pragma unroll
                    for (int c = 4; c < 8; ++c)
                        accm = __builtin_amdgcn_mfma_f32_16x16x32_f16(a[c], wbm[c], accm, 0, 0, 0);
#pragma unroll
                    for (int i = 0; i < 4; ++i) {
                        nsvL[i] = fmaxf(accn[i] + nsb_c, 0.0f);
                        s_NSh[cur][(q4 + i) * NROW + colw] = (_Float16)nsvL[i];
                    }
                    accmL = accm;
                }
                if (PcU > 0) {
                    floatx4 accn = {0, 0, 0, 0}, accm = {0, 0, 0, 0};
                    const _Float16* xrow = s_Xh[cur] + (16 + lm) * WROW + (quad << 3);
                    half8 a[8];
#pragma unroll
                    for (int c = 0; c < 8; ++c) a[c] = *(const half8*)(xrow + (c << 5));
#pragma unroll
                    for (int c = 0; c < 8; ++c)
                        accn = __builtin_amdgcn_mfma_f32_16x16x32_f16(a[c], wbn[c], accn, 0, 0, 0);
#pragma unroll
                    for (int c = 4; c < 8; ++c)
                        accm = __builtin_amdgcn_mfma_f32_16x16x32_f16(a[c], wbm[c], accm, 0, 0, 0);
#pragma unroll
                    for (int i = 0; i < 4; ++i) {
                        nsvU[i] = fmaxf(accn[i] + nsb_c, 0.0f);
                        s_NSh[cur][(16 + q4 + i) * NROW + colw] = (_Float16)nsvU[i];
                    }
                    accmU = accm;
                }
                // rotate pipeline state
                accmPL = accmL; accmPU = accmU;
#pragma unroll
                for (int i = 0; i < 4; ++i) { nsvPL[i] = nsvL[i]; nsvPU[i] = nsvU[i]; }
                zredCL = zredNL; zredCU = zredNU;
                bar_lds();       // publish Xh[nxt], NSh[cur], NMh[nxt], rna[cur]
            }
            // ---- fused interval: NEXT-round marking overlapped with epilogue F ----
            // (tact stable: last E published by the final loop barrier; marking
            //  touches s_mark only — disjoint from epilogue's global/NSh traffic)
            rem2a = remA && (s_tact[nodeA] <= 1.0f - 1e-7f);
            rem2b = remB && (s_tact[nodeB] <= 1.0f - 1e-7f);
            if (rem2a) atomicMin(&s_mark[nodeA], t);
            if (rem2b) atomicMin(&s_mark[nodeB], NT + t);
            if (t == 0) s_cnt = 0;
            {
                const int c0L = ((Pr - 1) >> 5) << 5;    // last superchunk base
                const int pbL = (c0L >> 5) & 1;
                const int lastn = Pr - c0L;
                const int PcLL = (lastn >= 16) ? 16 : lastn;
                const int PcLU = (lastn > 16) ? lastn - 16 : 0;
                if (Pr > 32) {                           // copy superchunk K-1 (full)
                    const int sbC = sb0 + c0L - 32;
                    const uint4 v = *(const uint4*)(s_NMh[pbL ^ 1] + rowc * NROW + (c16 << 3));
                    *(uint4*)(nmbuf_h + (size_t)(sbC + rowc) * M + (c16 << 3)) = v;
                }
                // phase2 DIRECT for last superchunk (partial-capable)
                {
                    const _Float16* nrow = s_NSh[pbL] + lm * NROW + (quad << 3);
#pragma unroll
                    for (int c = 0; c < 4; ++c)
                        accmPL = __builtin_amdgcn_mfma_f32_16x16x32_f16(
                            *(const half8*)(nrow + (c << 5)), wbm[c], accmPL, 0, 0, 0);
                }
                if (PcLU > 0) {
                    const _Float16* nrow = s_NSh[pbL] + (16 + lm) * NROW + (quad << 3);
#pragma unroll
                    for (int c = 0; c < 4; ++c)
                        accmPU = __builtin_amdgcn_mfma_f32_16x16x32_f16(
                            *(const half8*)(nrow + (c << 5)), wbm[c], accmPU, 0, 0, 0);
                }
                const int sbL = sb0 + c0L;
#pragma unroll
                for (int i = 0; i < 4; ++i) {
                    const int r = q4 + i;
                    if (r < PcLL) {
                        nmbuf_h[(size_t)(sbL + r) * M + colw] =
                            (_Float16)(accmPL[i] + nmb_c);
                        atomicAdd(finalv + (size_t)s_rnode[c0L + r] * H + colw,
                                  nsvPL[i] * s_rna[pbL][r]);
                    }
                    if (r < PcLU) {
                        nmbuf_h[(size_t)(sbL + 16 + r) * M + colw] =
                            (_Float16)(accmPU[i] + nmb_c);
                        atomicAdd(finalv + (size_t)s_rnode[c0L + 16 + r] * H + colw,
                                  nsvPU[i] * s_rna[pbL][16 + r]);
                    }
                }
                // coalesced feats copy (guarded)
                if (rowc < PcLL || (unsigned)(rowc - 16) < (unsigned)PcLU) {
                    const int nrr = (int)s_rnode[c0L + rowc];
                    const uint4 v = *(const uint4*)(s_NSh[pbL] + rowc * NROW + (c16 << 3));
                    *(uint4*)(feats_h + (size_t)nrr * H + (c16 << 3)) = v;
                }
            }
            // loop continues: next bar_lds() at loop top serves as R1
        }

        // -------- enqueue (queue order via two-class prefix over flags) --------
        const bool pfa = (s_flag[t] & 1) != 0;
        const bool pfb = (s_flag[t] & 2) != 0;
        const unsigned long long mfa = __ballot(pfa);
        const unsigned long long mfb = __ballot(pfb);
        if (lane == 0) { s_wc[wid] = __popcll(mfa); s_wd[wid] = __popcll(mfb); }
        bar_lds();                                       // B3
        int TA = 0, TB = 0, preA = 0, preB = 0;
#pragma unroll
        for (int w = 0; w < 8; ++w) {
            TA += s_wc[w]; TB += s_wd[w];
            preA += (w < wid) ? s_wc[w] : 0;
            preB += (w < wid) ? s_wd[w] : 0;
        }
        const int T = TA + TB;
        if (T > 0) {
            const unsigned long long below = (1ull << lane) - 1ull;
            if (pfa) s_order[preA + __popcll(mfa & below)] = (short)t;
            if (pfb) s_order[TA + preB + __popcll(mfb & below)] = (short)(NT + t);
            bar_lds();                                   // B4
            for (int idx = t; idx < T * DEG; idx += NT) {
                const int e = (int)s_order[idx >> 4];
                const unsigned v = s_enq[e];
                const int nd = (int)(v & 0xffffu);
                const unsigned slot = v >> 16;
                const int q = tail + idx;
                if (q < QCAP)
                    s_q[q] = (unsigned)s_nb[nd * DEG + (idx & 15)] | (slot << 16);
            }
        }
        tail += DEG * T;
        gbase += T;
        head += W;
        bar_lds();                                       // B5 (LDS-only): s_q visible
    }

    // drain outstanding finalv atomics / stores before readout
    __syncthreads();

    // ---- readout (g/lg overlaid on dead mark region) ----
    if (t < H) {
        float g0 = 0, g1 = 0, g2 = 0, g3 = 0;
        for (int n = 0; n < NN; n += 4) {
            g0 += finalv[(n + 0) * H + t];
            g1 += finalv[(n + 1) * H + t];
            g2 += finalv[(n + 2) * H + t];
            g3 += finalv[(n + 3) * H + t];
        }
        s_g[t] = (g0 + g1) + (g2 + g3);
    }
    __syncthreads();
    if (t < PP * OUTF) {
        const int pp = t / OUTF, o = t % OUTF;
        float acc = dec_b[pp * OUTF + o];
        for (int h = 0; h < H; ++h) acc += s_g[h] * dec_w[(pp * H + h) * OUTF + o];
        s_lg[t] = acc;
    }
    __syncthreads();
    if (t < PP * OUTF) {
        const int pp = t / OUTF;
        float mx = -INFINITY;
        for (int o = 0; o < OUTF; ++o) mx = fmaxf(mx, s_lg[pp * OUTF + o]);
        float s = 0.0f;
        for (int o = 0; o < OUTF; ++o) s += expf(s_lg[pp * OUTF + o] - mx);
        out[t] = s_lg[t] - (mx + logf(s));
    }
}

extern "C" void kernel_launch(void* const* d_in, const int* in_sizes, int n_in,
                              void* d_out, int out_size, void* d_ws, size_t ws_size,
                              hipStream_t stream) {
    const float* xa        = (const float*)d_in[0];
    const float* fm        = (const float*)d_in[1];
    const int*   neighbors = (const int*)  d_in[2];
    const int*   nstart_p  = (const int*)  d_in[3];
    const float* enc_w     = (const float*)d_in[4];
    const float* enc_b     = (const float*)d_in[5];
    const float* ns_w      = (const float*)d_in[6];
    const float* ns_b      = (const float*)d_in[7];
    const float* nm_w      = (const float*)d_in[8];
    const float* nm_b      = (const float*)d_in[9];
    const float* act_w     = (const float*)d_in[10];
    const float* act_b     = (const float*)d_in[11];
    const float* dec_w     = (const float*)d_in[12];
    const float* dec_b     = (const float*)d_in[13];
    float* out = (float*)d_out;

    char* w = (char*)d_ws;
    _Float16* feats_h = (_Float16*)w;                 w += (size_t)NN * H * 2;
    float*    finalv  = (float*)w;                    w += (size_t)NN * H * 4;
    _Float16* nmbuf_h = (_Float16*)w;                 w += (size_t)NSLOT * M * 2;
    _Float16* wnsB    = (_Float16*)w;                 w += (size_t)128 * WROW * 2;
    _Float16* wnmB    = (_Float16*)w;                 w += (size_t)128 * WROW * 2;
    unsigned int* qpack = (unsigned int*)w;           // unused (LDS queue)

    init_kernel<<<NN, 128, 0, stream>>>(xa, fm, enc_w, enc_b, nstart_p,
                                        feats_h, finalv, nmbuf_h);
    pack_kernel<<<132, 256, 0, stream>>>(ns_w, nm_w, wnsB, wnmB);
    seq_kernel<<<1, NT, 0, stream>>>(neighbors, ns_b, nm_b,
                                     act_w, act_b, dec_w, dec_b, nstart_p,
                                     wnsB, wnmB,
                                     feats_h, finalv, nmbuf_h, qpack, out);
}